// Round 2
// baseline (813.591 us; speedup 1.0000x reference)
//
#include <hip/hip_runtime.h>

// ---------------------------------------------------------------------------
// WindowAttention on MI355X (gfx950).
// R2 restructure: the R1 fused attn kernel was latency-bound (MfmaUtil 3.9%,
// VALUBusy 10%, Occupancy 23.6% = 2 blocks/CU, ~99% stall from barrier-locked
// per-head dependency chains). New pipeline (fast path, needs 196 MB ws):
//   prep      : weight transpose + bf16 cast + bias table [6][224][64] f32
//   qkv_kernel: per-window QKV GEMM, no LDS, no barriers; writes q/k/v bf16
//               to ws in attention-friendly layouts (k rows / v^T keys padded
//               with exact zeros).
//   attn2     : ONE INDEPENDENT WAVE PER (window, head) — no __syncthreads;
//               per-wave LDS strip only for P C->A layout round trip.
//   proj      : in-place, LDS-staging removed (wave read-set == write-set,
//               so staging was never needed), split-bf16 3-pass MFMA.
// Fallback path (small ws): R1 fused attn + same proj.
// All matmuls v_mfma_f32_16x16x32_bf16. Fragment layouts (m89/m91-verified):
// A/B: elem j -> [lane&15][quad*8+j] (K-major); C/D: col=lane&15, row=quad*4+r.
// ---------------------------------------------------------------------------

typedef __attribute__((ext_vector_type(8))) short bf16x8;
typedef __attribute__((ext_vector_type(4))) float f32x4;

#define MFMA16(a, b, c) __builtin_amdgcn_mfma_f32_16x16x32_bf16((a), (b), (c), 0, 0, 0)

// ws layout. ushort-unit offsets for bf16 regions, f32-unit for bias table.
#define WS_QKVT  0         // [192][192]  qkv_w^T   bf16
#define WS_QKV2T 36864     // [384][192]  qkv2_w^T  bf16
#define WS_PROJH 110592    // [192][192]  proj_w^T  hi bf16
#define WS_PROJL 147456    // [192][192]  proj_w^T  lo bf16
#define BIAS_F32 92160     // byte 368,640: [6][224][64] f32 bias table (86,016 f32)
#define QG_U16   524288    // byte 1,048,576: q  bf16 [6144][64][32]
#define KG_U16   13107200  // k  bf16 [6144][208][32] (rows 196..207 == 0)
#define VTG_U16  54001664  // v^T bf16 [6144][32][224] (keys 196..223 == 0)
#define WS_NEEDED 196083712ull

#define SCALE_Q 0.17677669529663687f   // 32^-0.5

__device__ __forceinline__ unsigned short f2bf(float f) {
  unsigned int u = __float_as_uint(f);
  u += 0x7fffu + ((u >> 16) & 1u);     // round-to-nearest-even
  return (unsigned short)(u >> 16);
}
__device__ __forceinline__ float bf2f(unsigned short s) {
  return __uint_as_float(((unsigned int)s) << 16);
}
// load 8 consecutive fp32 (32B, aligned) -> bf16x8 fragment
__device__ __forceinline__ bf16x8 cvt8(const float* __restrict__ p) {
  union { bf16x8 v; unsigned short s[8]; } U;
  float4 v0 = *(const float4*)p;
  float4 v1 = *(const float4*)(p + 4);
  U.s[0] = f2bf(v0.x); U.s[1] = f2bf(v0.y); U.s[2] = f2bf(v0.z); U.s[3] = f2bf(v0.w);
  U.s[4] = f2bf(v1.x); U.s[5] = f2bf(v1.y); U.s[6] = f2bf(v1.z); U.s[7] = f2bf(v1.w);
  return U.v;
}

// ---------------------------------------------------------------------------
// prep: W^T bf16 casts + (fast path, grid=912) bias table.
// biasT[h][key][qrow] f32: -1e30 for key>=196 (mask), 0 for qrow>=49 (pad),
// else btab[rel_idx(qrow,key)*6+h]. Matches attn C-layout: float4 over qrow.
// ---------------------------------------------------------------------------
__global__ void prep_kernel(const float* __restrict__ qkv_w,
                            const float* __restrict__ qkv2_w,
                            const float* __restrict__ proj_w,
                            const float* __restrict__ btab,
                            unsigned short* __restrict__ ws) {
  int t = blockIdx.x * 256 + threadIdx.x;
  if (t < 36864) {                       // qkv_w (192x192), reads coalesced
    int k = t / 192, n = t % 192;
    ws[WS_QKVT + n * 192 + k] = f2bf(qkv_w[t]);
  } else if (t < 110592) {               // qkv2_w (192x384)
    int u = t - 36864;
    int k = u / 384, n = u % 384;
    ws[WS_QKV2T + n * 192 + k] = f2bf(qkv2_w[u]);
  } else if (t < 147456) {               // proj_w (192x192) hi/lo split
    int u = t - 110592;
    int k = u / 192, n = u % 192;
    float p = proj_w[u];
    unsigned short hi = f2bf(p);
    ws[WS_PROJH + n * 192 + k] = hi;
    ws[WS_PROJL + n * 192 + k] = f2bf(p - bf2f(hi));
  } else if (t < 233472) {               // bias table [6][224][64] f32
    int u = t - 147456;
    int h = u / 14336;
    int r2 = u - h * 14336;
    int key = r2 >> 6, qrow = r2 & 63;
    float v;
    if (key >= 196)      v = -1e30f;     // key-pad mask
    else if (qrow >= 49) v = 0.f;        // query pad: finite, rows discarded
    else {
      int jh = key / 14, jw = key - 14 * jh;
      int ih = qrow / 7, iw = qrow - 7 * ih;
      v = btab[((ih - jh + 13) * 20 + (iw - jw + 13)) * 6 + h];
    }
    ((float*)ws)[BIAS_F32 + u] = v;
  }
}

// ---------------------------------------------------------------------------
// qkv_kernel: one block (4 waves) per window. NO LDS, NO BARRIERS.
// x1/x2 A-fragments converted once into registers; per head, q/k/v tiles
// computed by MFMA and stored bf16 to ws (L2 write-combining handles the
// v^T 8B-granular stores).
// ---------------------------------------------------------------------------
__launch_bounds__(256, 2)
__global__ void qkv_kernel(const float* __restrict__ x1,
                           const float* __restrict__ x2,
                           const float* __restrict__ qkv_b,
                           const float* __restrict__ qkv2_b,
                           unsigned short* __restrict__ ws) {
  const int tid  = threadIdx.x;
  const int wave = tid >> 6;
  const int lane = tid & 63;
  const int l16  = lane & 15;
  const int quad = lane >> 4;
  const int b    = blockIdx.x;

  const float* x1b = x1 + (size_t)b * (49 * 192);
  const float* x2b = x2 + (size_t)b * (196 * 192);
  unsigned short* qg = ws + QG_U16  + (size_t)b * 6 * 2048;
  unsigned short* kg = ws + KG_U16  + (size_t)b * 6 * 6656;
  unsigned short* vg = ws + VTG_U16 + (size_t)b * 6 * 7168;

  // zero v^T pad keys 208..223 for all 6 heads (u32 stores, aligned)
  for (int i = tid; i < 1536; i += 256) {
    int hh = i >> 8, j = i & 255;        // d = j>>3, col pair = j&7
    *(unsigned int*)(vg + hh * 7168 + (j >> 3) * 224 + 208 + (j & 7) * 2) = 0u;
  }

  // head-invariant A-fragments, converted ONCE
  bf16x8 x1f[6];
  {
    const int m = wave * 16 + l16;
    const bool mv = (m < 49);
#pragma unroll
    for (int kk = 0; kk < 6; ++kk)
      x1f[kk] = mv ? cvt8(x1b + m * 192 + kk * 32 + quad * 8)
                   : bf16x8{0, 0, 0, 0, 0, 0, 0, 0};
  }
  bf16x8 x2f[3][6];
#pragma unroll
  for (int ti = 0; ti < 3; ++ti) {
    const int m = (wave + ti * 4) * 16 + l16;   // < 192: all rows real
#pragma unroll
    for (int kk = 0; kk < 6; ++kk)
      x2f[ti][kk] = cvt8(x2b + m * 192 + kk * 32 + quad * 8);
  }

  for (int h = 0; h < 6; ++h) {
    // ---- q_h = (x1 @ Wq_h + b) * SCALE  -> qg[h][64][32] (pad rows finite)
    {
      f32x4 a0{0.f, 0.f, 0.f, 0.f}, a1{0.f, 0.f, 0.f, 0.f};
#pragma unroll
      for (int kk = 0; kk < 6; ++kk) {
        const unsigned short* wq = ws + WS_QKVT + (h * 32 + l16) * 192 + kk * 32 + quad * 8;
        a0 = MFMA16(x1f[kk], *(const bf16x8*)(wq), a0);
        a1 = MFMA16(x1f[kk], *(const bf16x8*)(wq + 16 * 192), a1);
      }
      const float b0 = qkv_b[h * 32 + l16];
      const float b1 = qkv_b[h * 32 + 16 + l16];
      unsigned short* qh = qg + h * 2048;
#pragma unroll
      for (int r = 0; r < 4; ++r) {
        const int row = wave * 16 + quad * 4 + r;
        qh[row * 32 + l16]      = f2bf((a0[r] + b0) * SCALE_Q);
        qh[row * 32 + 16 + l16] = f2bf((a1[r] + b1) * SCALE_Q);
      }
    }
    // ---- k_h, v_h = x2 @ Wkv_h + b -> kg[h][208][32], vg[h][32][224]
    const float bk0 = qkv2_b[h * 32 + l16];
    const float bk1 = qkv2_b[h * 32 + 16 + l16];
    const float bv0 = qkv2_b[192 + h * 32 + l16];
    const float bv1 = qkv2_b[192 + h * 32 + 16 + l16];
    unsigned short* kh = kg + h * 6656;
    unsigned short* vh = vg + h * 7168;
#pragma unroll
    for (int ti = 0; ti < 3; ++ti) {
      const int mt = wave + ti * 4;      // <= 11: every row real
      f32x4 a0{0.f, 0.f, 0.f, 0.f}, a1{0.f, 0.f, 0.f, 0.f};
      f32x4 a2{0.f, 0.f, 0.f, 0.f}, a3{0.f, 0.f, 0.f, 0.f};
#pragma unroll
      for (int kk = 0; kk < 6; ++kk) {
        const unsigned short* wk = ws + WS_QKV2T + (h * 32 + l16) * 192 + kk * 32 + quad * 8;
        a0 = MFMA16(x2f[ti][kk], *(const bf16x8*)(wk), a0);
        a1 = MFMA16(x2f[ti][kk], *(const bf16x8*)(wk + 16 * 192), a1);
        a2 = MFMA16(x2f[ti][kk], *(const bf16x8*)(wk + 192 * 192), a2);
        a3 = MFMA16(x2f[ti][kk], *(const bf16x8*)(wk + 208 * 192), a3);
      }
#pragma unroll
      for (int r = 0; r < 4; ++r) {
        const int row = mt * 16 + quad * 4 + r;     // < 192: unguarded
        kh[row * 32 + l16]        = f2bf(a0[r] + bk0);
        kh[row * 32 + 16 + l16]   = f2bf(a1[r] + bk1);
        vh[l16 * 224 + row]       = f2bf(a2[r] + bv0);
        vh[(16 + l16) * 224 + row] = f2bf(a3[r] + bv1);
      }
    }
    if (wave == 0) {                     // ragged tile: rows 192..207
      f32x4 a0{0.f, 0.f, 0.f, 0.f}, a1{0.f, 0.f, 0.f, 0.f};
      f32x4 a2{0.f, 0.f, 0.f, 0.f}, a3{0.f, 0.f, 0.f, 0.f};
      const int m = 192 + l16;
      const bool mv = (m < 196);
#pragma unroll
      for (int kk = 0; kk < 6; ++kk) {
        bf16x8 a = mv ? cvt8(x2b + m * 192 + kk * 32 + quad * 8)
                      : bf16x8{0, 0, 0, 0, 0, 0, 0, 0};
        const unsigned short* wk = ws + WS_QKV2T + (h * 32 + l16) * 192 + kk * 32 + quad * 8;
        a0 = MFMA16(a, *(const bf16x8*)(wk), a0);
        a1 = MFMA16(a, *(const bf16x8*)(wk + 16 * 192), a1);
        a2 = MFMA16(a, *(const bf16x8*)(wk + 192 * 192), a2);
        a3 = MFMA16(a, *(const bf16x8*)(wk + 208 * 192), a3);
      }
#pragma unroll
      for (int r = 0; r < 4; ++r) {
        const int row = 192 + quad * 4 + r;
        const bool rv = (row < 196);     // rows 196..207 get EXACT zeros
        kh[row * 32 + l16]        = rv ? f2bf(a0[r] + bk0) : (unsigned short)0;
        kh[row * 32 + 16 + l16]   = rv ? f2bf(a1[r] + bk1) : (unsigned short)0;
        vh[l16 * 224 + row]       = rv ? f2bf(a2[r] + bv0) : (unsigned short)0;
        vh[(16 + l16) * 224 + row] = rv ? f2bf(a3[r] + bv1) : (unsigned short)0;
      }
    }
  }
}

// ---------------------------------------------------------------------------
// attn2: one independent wave per (window, head). 4 waves/block, NO barriers.
// Per-wave LDS strip [16][232] bf16 for the P C-layout -> A-layout round trip
// (stride 232: 2-way banks = free). k/v/q/bias read straight from ws (L2-hot:
// 12.5+14+4 KB per wave re-read 4x by the same wave).
// ---------------------------------------------------------------------------
__launch_bounds__(256, 4)
__global__ void attn2_kernel(const unsigned short* __restrict__ ws,
                             float* __restrict__ out) {
  __shared__ unsigned short ps4[4][16 * 232];   // 29,696 B
  const int tid  = threadIdx.x;
  const int wave = tid >> 6;
  const int lane = tid & 63;
  const int l16  = lane & 15;
  const int quad = lane >> 4;
  const int wid  = blockIdx.x * 4 + wave;       // < 6144
  const int win  = wid / 6, head = wid - win * 6;

  const unsigned short* qb = ws + QG_U16  + (size_t)wid * 2048;
  const unsigned short* kb = ws + KG_U16  + (size_t)wid * 6656;
  const unsigned short* vb = ws + VTG_U16 + (size_t)wid * 7168;
  const float* bbt = (const float*)ws + BIAS_F32 + head * 14336;
  unsigned short* ps = ps4[wave];
  float* ob = out + (size_t)win * 9408 + head * 32;

  // zero strip pad cols 208..231 once (P cols 0..207 rewritten every m-tile)
  for (int i = lane; i < 192; i += 64) {
    int rr = i / 12, cc = (i - rr * 12) * 2;
    *(unsigned int*)(ps + rr * 232 + 208 + cc) = 0u;
  }

  for (int mt = 0; mt < 4; ++mt) {
    // ---- logits = q k^T + bias (bias/mask preloaded as MFMA C-init) ----
    bf16x8 aq = *(const bf16x8*)(qb + (mt * 16 + l16) * 32 + quad * 8);
    f32x4 lg[13];
#pragma unroll
    for (int nt = 0; nt < 13; ++nt)
      lg[nt] = *(const f32x4*)(bbt + (nt * 16 + l16) * 64 + mt * 16 + quad * 4);
#pragma unroll
    for (int nt = 0; nt < 13; ++nt)
      lg[nt] = MFMA16(aq, *(const bf16x8*)(kb + (nt * 16 + l16) * 32 + quad * 8), lg[nt]);

    // ---- row softmax (row = quad*4+r on the 16 lanes of one quad) ----
#pragma unroll
    for (int r = 0; r < 4; ++r) {
      float mx = lg[0][r];
#pragma unroll
      for (int nt = 1; nt < 13; ++nt) mx = fmaxf(mx, lg[nt][r]);
      mx = fmaxf(mx, __shfl_xor(mx, 1));
      mx = fmaxf(mx, __shfl_xor(mx, 2));
      mx = fmaxf(mx, __shfl_xor(mx, 4));
      mx = fmaxf(mx, __shfl_xor(mx, 8));
      float s = 0.f;
#pragma unroll
      for (int nt = 0; nt < 13; ++nt) {
        float p = __expf(lg[nt][r] - mx);
        lg[nt][r] = p;
        s += p;
      }
      s += __shfl_xor(s, 1);
      s += __shfl_xor(s, 2);
      s += __shfl_xor(s, 4);
      s += __shfl_xor(s, 8);
      const float inv = 1.f / s;
      const int row = quad * 4 + r;     // garbage window-rows written too;
#pragma unroll                          // their PV output is discarded below
      for (int nt = 0; nt < 13; ++nt)
        ps[row * 232 + nt * 16 + l16] = f2bf(lg[nt][r] * inv);
    }

    // ---- out tile = P @ V (K padded to 224 with exact zeros) ----
    f32x4 o0{0.f, 0.f, 0.f, 0.f}, o1{0.f, 0.f, 0.f, 0.f};
#pragma unroll
    for (int kk = 0; kk < 7; ++kk) {
      bf16x8 a  = *(const bf16x8*)(ps + l16 * 232 + kk * 32 + quad * 8);
      bf16x8 b0 = *(const bf16x8*)(vb + l16 * 224 + kk * 32 + quad * 8);
      bf16x8 b1 = *(const bf16x8*)(vb + (16 + l16) * 224 + kk * 32 + quad * 8);
      o0 = MFMA16(a, b0, o0);
      o1 = MFMA16(a, b1, o1);
    }
#pragma unroll
    for (int r = 0; r < 4; ++r) {
      const int row = mt * 16 + quad * 4 + r;
      if (row < 49) {
        float* op = ob + row * 192;
        op[l16]      = o0[r];
        op[16 + l16] = o1[r];
      }
    }
  }
}

// ---------------------------------------------------------------------------
// R1 fused attention kernel — retained verbatim as the small-ws fallback.
// ---------------------------------------------------------------------------
__launch_bounds__(256, 2)
__global__ void attn_kernel(const float* __restrict__ x1,
                            const float* __restrict__ x2,
                            const float* __restrict__ qkv_b,
                            const float* __restrict__ qkv2_b,
                            const float* __restrict__ btab,   // [400][6]
                            const unsigned short* __restrict__ ws,
                            float* __restrict__ out) {
  extern __shared__ char smem[];
  unsigned short* ksm = (unsigned short*)(smem);
  unsigned short* vtm = (unsigned short*)(smem + 15680);
  unsigned short* atm = (unsigned short*)(smem + 30528);
  unsigned short* qhm = (unsigned short*)(smem + 60224);

  const int tid  = threadIdx.x;
  const int wave = tid >> 6;
  const int lane = tid & 63;
  const int l16  = lane & 15;
  const int quad = lane >> 4;
  const int b    = blockIdx.x;

  const float* x1b = x1 + (size_t)b * (49 * 192);
  const float* x2b = x2 + (size_t)b * (196 * 192);

  {
    int* z = (int*)(smem + 30528);
    for (int i = tid; i < 29696 / 4; i += 256) z[i] = 0;
    int* z2 = (int*)(smem + 15680);
    for (int i = tid; i < 14848 / 4; i += 256) z2[i] = 0;
  }

  int Pr6[4];
#pragma unroll
  for (int r = 0; r < 4; ++r) {
    int i = wave * 16 + quad * 4 + r;
    if (i > 48) i = 48;
    int ih = i / 7, iw = i - 7 * ih;
    Pr6[r] = (ih * 20 + iw + 273) * 6;
  }
  int qj6[13];
#pragma unroll
  for (int nt = 0; nt < 13; ++nt) {
    int jc = nt * 16 + l16;
    if (jc > 195) jc = 195;
    int jh = jc / 14, jw = jc - 14 * jh;
    qj6[nt] = (jh * 20 + jw) * 6;
  }

  bf16x8 x1f[6];
  {
    const int m = wave * 16 + l16;
    const bool mv = (m < 49);
#pragma unroll
    for (int kk = 0; kk < 6; ++kk) {
      if (mv) x1f[kk] = cvt8(x1b + m * 192 + kk * 32 + quad * 8);
      else    x1f[kk] = bf16x8{0, 0, 0, 0, 0, 0, 0, 0};
    }
  }
  bf16x8 x2f[3][6];
#pragma unroll
  for (int ti = 0; ti < 3; ++ti) {
    const int m = (wave + ti * 4) * 16 + l16;
#pragma unroll
    for (int kk = 0; kk < 6; ++kk)
      x2f[ti][kk] = cvt8(x2b + m * 192 + kk * 32 + quad * 8);
  }

  __syncthreads();

  for (int h = 0; h < 6; ++h) {
    {
      f32x4 acc0{0.f, 0.f, 0.f, 0.f}, acc1{0.f, 0.f, 0.f, 0.f};
#pragma unroll
      for (int kk = 0; kk < 6; ++kk) {
        const unsigned short* wq = ws + WS_QKVT + (h * 32 + l16) * 192 + kk * 32 + quad * 8;
        acc0 = MFMA16(x1f[kk], *(const bf16x8*)(wq), acc0);
        acc1 = MFMA16(x1f[kk], *(const bf16x8*)(wq + 16 * 192), acc1);
      }
      const float bia0 = qkv_b[h * 32 + l16];
      const float bia1 = qkv_b[h * 32 + 16 + l16];
#pragma unroll
      for (int r = 0; r < 4; ++r) {
        const int row = wave * 16 + quad * 4 + r;
        qhm[row * 40 + l16]      = f2bf((acc0[r] + bia0) * SCALE_Q);
        qhm[row * 40 + 16 + l16] = f2bf((acc1[r] + bia1) * SCALE_Q);
      }
    }
    const float bk0 = qkv2_b[h * 32 + l16];
    const float bk1 = qkv2_b[h * 32 + 16 + l16];
    const float bv0 = qkv2_b[192 + h * 32 + l16];
    const float bv1 = qkv2_b[192 + h * 32 + 16 + l16];
#pragma unroll
    for (int ti = 0; ti < 3; ++ti) {
      const int mt = wave + ti * 4;
      f32x4 acc0{0.f, 0.f, 0.f, 0.f}, acc1{0.f, 0.f, 0.f, 0.f};
      f32x4 acc2{0.f, 0.f, 0.f, 0.f}, acc3{0.f, 0.f, 0.f, 0.f};
#pragma unroll
      for (int kk = 0; kk < 6; ++kk) {
        const unsigned short* wk = ws + WS_QKV2T + (h * 32 + l16) * 192 + kk * 32 + quad * 8;
        acc0 = MFMA16(x2f[ti][kk], *(const bf16x8*)(wk), acc0);
        acc1 = MFMA16(x2f[ti][kk], *(const bf16x8*)(wk + 16 * 192), acc1);
        acc2 = MFMA16(x2f[ti][kk], *(const bf16x8*)(wk + 192 * 192), acc2);
        acc3 = MFMA16(x2f[ti][kk], *(const bf16x8*)(wk + 208 * 192), acc3);
      }
#pragma unroll
      for (int r = 0; r < 4; ++r) {
        const int row = mt * 16 + quad * 4 + r;
        ksm[row * 40 + l16]      = f2bf(acc0[r] + bk0);
        ksm[row * 40 + 16 + l16] = f2bf(acc1[r] + bk1);
        vtm[l16 * 232 + row]        = f2bf(acc2[r] + bv0);
        vtm[(16 + l16) * 232 + row] = f2bf(acc3[r] + bv1);
      }
    }
    if (wave == 0) {
      f32x4 acc0{0.f, 0.f, 0.f, 0.f}, acc1{0.f, 0.f, 0.f, 0.f};
      f32x4 acc2{0.f, 0.f, 0.f, 0.f}, acc3{0.f, 0.f, 0.f, 0.f};
      const int m = 192 + l16;
      const bool mv = (m < 196);
#pragma unroll
      for (int kk = 0; kk < 6; ++kk) {
        const int k0 = kk * 32 + quad * 8;
        bf16x8 a;
        if (mv) a = cvt8(x2b + m * 192 + k0);
        else    a = bf16x8{0, 0, 0, 0, 0, 0, 0, 0};
        const unsigned short* wk = ws + WS_QKV2T + (h * 32 + l16) * 192 + k0;
        acc0 = MFMA16(a, *(const bf16x8*)(wk), acc0);
        acc1 = MFMA16(a, *(const bf16x8*)(wk + 16 * 192), acc1);
        acc2 = MFMA16(a, *(const bf16x8*)(wk + 192 * 192), acc2);
        acc3 = MFMA16(a, *(const bf16x8*)(wk + 208 * 192), acc3);
      }
#pragma unroll
      for (int r = 0; r < 4; ++r) {
        const int row = 192 + quad * 4 + r;
        if (row < 196) {
          ksm[row * 40 + l16]      = f2bf(acc0[r] + bk0);
          ksm[row * 40 + 16 + l16] = f2bf(acc1[r] + bk1);
        }
        vtm[l16 * 232 + row]        = f2bf(acc2[r] + bv0);
        vtm[(16 + l16) * 232 + row] = f2bf(acc3[r] + bv1);
      }
    }
    __syncthreads();

    f32x4 lg[13];
    {
      const int m = wave * 16 + l16;
      bf16x8 a = *(const bf16x8*)(qhm + m * 40 + quad * 8);
#pragma unroll
      for (int nt = 0; nt < 12; ++nt) {
#pragma unroll
        for (int r = 0; r < 4; ++r) lg[nt][r] = btab[Pr6[r] - qj6[nt] + h];
      }
#pragma unroll
      for (int r = 0; r < 4; ++r)
        lg[12][r] = (l16 < 4) ? btab[Pr6[r] - qj6[12] + h] : -1e30f;
#pragma unroll
      for (int nt = 0; nt < 13; ++nt) {
        bf16x8 bb = *(const bf16x8*)(ksm + (nt * 16 + l16) * 40 + quad * 8);
        lg[nt] = MFMA16(a, bb, lg[nt]);
      }
#pragma unroll
      for (int r = 0; r < 4; ++r) {
        float mx = lg[0][r];
#pragma unroll
        for (int nt = 1; nt < 13; ++nt) mx = fmaxf(mx, lg[nt][r]);
        mx = fmaxf(mx, __shfl_xor(mx, 1));
        mx = fmaxf(mx, __shfl_xor(mx, 2));
        mx = fmaxf(mx, __shfl_xor(mx, 4));
        mx = fmaxf(mx, __shfl_xor(mx, 8));
        float s = 0.f;
#pragma unroll
        for (int nt = 0; nt < 13; ++nt) {
          float p = __expf(lg[nt][r] - mx);
          lg[nt][r] = p;
          s += p;
        }
        s += __shfl_xor(s, 1);
        s += __shfl_xor(s, 2);
        s += __shfl_xor(s, 4);
        s += __shfl_xor(s, 8);
        const float inv = 1.f / s;
        const int row = wave * 16 + quad * 4 + r;
        if (row < 49) {
#pragma unroll
          for (int nt = 0; nt < 13; ++nt)
            atm[row * 232 + nt * 16 + l16] = f2bf(lg[nt][r] * inv);
        }
      }
    }
    {
      f32x4 o0{0.f, 0.f, 0.f, 0.f}, o1{0.f, 0.f, 0.f, 0.f};
      const int m = wave * 16 + l16;
#pragma unroll
      for (int kk = 0; kk < 7; ++kk) {
        const int k0 = kk * 32 + quad * 8;
        bf16x8 a  = *(const bf16x8*)(atm + m * 232 + k0);
        bf16x8 b0 = *(const bf16x8*)(vtm + l16 * 232 + k0);
        bf16x8 b1 = *(const bf16x8*)(vtm + (16 + l16) * 232 + k0);
        o0 = MFMA16(a, b0, o0);
        o1 = MFMA16(a, b1, o1);
      }
#pragma unroll
      for (int r = 0; r < 4; ++r) {
        const int row = wave * 16 + quad * 4 + r;
        if (row < 49) {
          float* op = out + (size_t)b * 9408 + row * 192 + h * 32;
          op[l16]      = o0[r];
          op[16 + l16] = o1[r];
        }
      }
    }
    __syncthreads();
  }
}

// ---------------------------------------------------------------------------
// proj: in-place on d_out, NO LDS, NO barrier. Each wave's read-row set
// (m = wave*16+l16) equals its write-row set (wave*16+quad*4+r), and program
// order keeps all reads before stores -> in-place is race-free.
// Split-bf16 3-pass MFMA: C += Ah*Bh + Ah*Bl + Al*Bh (~fp32 quality).
// ---------------------------------------------------------------------------
__launch_bounds__(256, 4)
__global__ void proj_kernel(const float* __restrict__ proj_b,
                            const unsigned short* __restrict__ ws,
                            float* __restrict__ out) {
  const int tid  = threadIdx.x;
  const int wave = tid >> 6;
  const int lane = tid & 63;
  const int l16  = lane & 15;
  const int quad = lane >> 4;
  const size_t base = (size_t)blockIdx.x * 64 * 192;

  f32x4 pacc[12];
#pragma unroll
  for (int nt = 0; nt < 12; ++nt) pacc[nt] = f32x4{0.f, 0.f, 0.f, 0.f};

  const int m = wave * 16 + l16;
  const float* ap0 = out + base + m * 192;
#pragma unroll
  for (int kk = 0; kk < 6; ++kk) {
    const int k0 = kk * 32 + quad * 8;
    float4 v0 = *(const float4*)(ap0 + k0);
    float4 v1 = *(const float4*)(ap0 + k0 + 4);
    float f[8] = {v0.x, v0.y, v0.z, v0.w, v1.x, v1.y, v1.z, v1.w};
    union { bf16x8 v; unsigned short s[8]; } H, L;
#pragma unroll
    for (int j = 0; j < 8; ++j) {
      H.s[j] = f2bf(f[j]);
      L.s[j] = f2bf(f[j] - bf2f(H.s[j]));
    }
#pragma unroll
    for (int nt = 0; nt < 12; ++nt) {
      bf16x8 bh = *(const bf16x8*)(ws + WS_PROJH + (nt * 16 + l16) * 192 + k0);
      bf16x8 bl = *(const bf16x8*)(ws + WS_PROJL + (nt * 16 + l16) * 192 + k0);
      pacc[nt] = MFMA16(H.v, bh, pacc[nt]);
      pacc[nt] = MFMA16(H.v, bl, pacc[nt]);
      pacc[nt] = MFMA16(L.v, bh, pacc[nt]);
    }
  }
#pragma unroll
  for (int nt = 0; nt < 12; ++nt) {
    const float pb = proj_b[nt * 16 + l16];
#pragma unroll
    for (int r = 0; r < 4; ++r) {
      const int row = wave * 16 + quad * 4 + r;
      out[base + row * 192 + nt * 16 + l16] = pacc[nt][r] + pb;
    }
  }
}

// ---------------------------------------------------------------------------
extern "C" void kernel_launch(void* const* d_in, const int* in_sizes, int n_in,
                              void* d_out, int out_size, void* d_ws, size_t ws_size,
                              hipStream_t stream) {
  const float* x1     = (const float*)d_in[0];
  const float* x2     = (const float*)d_in[1];
  const float* qkv_w  = (const float*)d_in[2];
  const float* qkv_b  = (const float*)d_in[3];
  const float* qkv2_w = (const float*)d_in[4];
  const float* qkv2_b = (const float*)d_in[5];
  const float* proj_w = (const float*)d_in[6];
  const float* proj_b = (const float*)d_in[7];
  const float* btab   = (const float*)d_in[8];
  unsigned short* ws  = (unsigned short*)d_ws;
  float* out          = (float*)d_out;
  (void)in_sizes; (void)n_in; (void)out_size;

  if (ws_size >= WS_NEEDED) {
    prep_kernel<<<dim3(912), dim3(256), 0, stream>>>(qkv_w, qkv2_w, proj_w, btab, ws);
    qkv_kernel<<<dim3(1024), dim3(256), 0, stream>>>(x1, x2, qkv_b, qkv2_b, ws);
    attn2_kernel<<<dim3(1536), dim3(256), 0, stream>>>(ws, out);
    proj_kernel<<<dim3(784), dim3(256), 0, stream>>>(proj_b, ws, out);
  } else {
    prep_kernel<<<dim3(576), dim3(256), 0, stream>>>(qkv_w, qkv2_w, proj_w, btab, ws);
    attn_kernel<<<dim3(1024), dim3(256), 65344, stream>>>(x1, x2, qkv_b, qkv2_b,
                                                          btab, ws, out);
    proj_kernel<<<dim3(784), dim3(256), 0, stream>>>(proj_b, ws, out);
  }
}

// Round 3
// 760.970 us; speedup vs baseline: 1.0691x; 1.0691x over previous
//
#include <hip/hip_runtime.h>

// ---------------------------------------------------------------------------
// WindowAttention on MI355X (gfx950).
// Pipeline (fast path, needs 196 MB ws):
//   prep      : weight transpose + bf16 cast + bias table [6][224][64] f32
//   qkv_kernel: per-window QKV GEMM. R3: v^T transposed through double-
//               buffered LDS -> fully coalesced global dumps (the R2 version
//               did 2B scalar stores with 64 lanes hitting 64 cache lines:
//               TA serialization made the kernel latency-bound at 375us).
//               kv weight fragments loaded once per kk and reused across all
//               3 m-tiles (was 3x redundant L2 traffic).
//   attn2     : ONE INDEPENDENT WAVE PER (window, head) — no __syncthreads.
//   proj      : in-place, no LDS, split-bf16 3-pass MFMA.
// Fallback path (small ws): R1 fused attn + same proj.
// All matmuls v_mfma_f32_16x16x32_bf16. Fragment layouts (m89/m91-verified):
// A/B: elem j -> [lane&15][quad*8+j] (K-major); C/D: col=lane&15, row=quad*4+r.
// ---------------------------------------------------------------------------

typedef __attribute__((ext_vector_type(8))) short bf16x8;
typedef __attribute__((ext_vector_type(4))) float f32x4;

#define MFMA16(a, b, c) __builtin_amdgcn_mfma_f32_16x16x32_bf16((a), (b), (c), 0, 0, 0)

// ws layout. ushort-unit offsets for bf16 regions, f32-unit for bias table.
#define WS_QKVT  0         // [192][192]  qkv_w^T   bf16
#define WS_QKV2T 36864     // [384][192]  qkv2_w^T  bf16
#define WS_PROJH 110592    // [192][192]  proj_w^T  hi bf16
#define WS_PROJL 147456    // [192][192]  proj_w^T  lo bf16
#define BIAS_F32 92160     // byte 368,640: [6][224][64] f32 bias table (86,016 f32)
#define QG_U16   524288    // byte 1,048,576: q  bf16 [6144][64][32]
#define KG_U16   13107200  // k  bf16 [6144][208][32] (rows 196..207 == 0)
#define VTG_U16  54001664  // v^T bf16 [6144][32][224] (keys 196..223 == 0)
#define WS_NEEDED 196083712ull

#define SCALE_Q 0.17677669529663687f   // 32^-0.5

__device__ __forceinline__ unsigned short f2bf(float f) {
  unsigned int u = __float_as_uint(f);
  u += 0x7fffu + ((u >> 16) & 1u);     // round-to-nearest-even
  return (unsigned short)(u >> 16);
}
__device__ __forceinline__ float bf2f(unsigned short s) {
  return __uint_as_float(((unsigned int)s) << 16);
}
// load 8 consecutive fp32 (32B, aligned) -> bf16x8 fragment
__device__ __forceinline__ bf16x8 cvt8(const float* __restrict__ p) {
  union { bf16x8 v; unsigned short s[8]; } U;
  float4 v0 = *(const float4*)p;
  float4 v1 = *(const float4*)(p + 4);
  U.s[0] = f2bf(v0.x); U.s[1] = f2bf(v0.y); U.s[2] = f2bf(v0.z); U.s[3] = f2bf(v0.w);
  U.s[4] = f2bf(v1.x); U.s[5] = f2bf(v1.y); U.s[6] = f2bf(v1.z); U.s[7] = f2bf(v1.w);
  return U.v;
}

// ---------------------------------------------------------------------------
// prep: W^T bf16 casts + bias table.
// biasT[h][key][qrow] f32: -1e30 for key>=196 (mask), 0 for qrow>=49 (pad),
// else btab[rel_idx(qrow,key)*6+h]. Matches attn C-layout: float4 over qrow.
// ---------------------------------------------------------------------------
__global__ void prep_kernel(const float* __restrict__ qkv_w,
                            const float* __restrict__ qkv2_w,
                            const float* __restrict__ proj_w,
                            const float* __restrict__ btab,
                            unsigned short* __restrict__ ws) {
  int t = blockIdx.x * 256 + threadIdx.x;
  if (t < 36864) {                       // qkv_w (192x192), reads coalesced
    int k = t / 192, n = t % 192;
    ws[WS_QKVT + n * 192 + k] = f2bf(qkv_w[t]);
  } else if (t < 110592) {               // qkv2_w (192x384)
    int u = t - 36864;
    int k = u / 384, n = u % 384;
    ws[WS_QKV2T + n * 192 + k] = f2bf(qkv2_w[u]);
  } else if (t < 147456) {               // proj_w (192x192) hi/lo split
    int u = t - 110592;
    int k = u / 192, n = u % 192;
    float p = proj_w[u];
    unsigned short hi = f2bf(p);
    ws[WS_PROJH + n * 192 + k] = hi;
    ws[WS_PROJL + n * 192 + k] = f2bf(p - bf2f(hi));
  } else if (t < 233472) {               // bias table [6][224][64] f32
    int u = t - 147456;
    int h = u / 14336;
    int r2 = u - h * 14336;
    int key = r2 >> 6, qrow = r2 & 63;
    float v;
    if (key >= 196)      v = -1e30f;     // key-pad mask
    else if (qrow >= 49) v = 0.f;        // query pad: finite, rows discarded
    else {
      int jh = key / 14, jw = key - 14 * jh;
      int ih = qrow / 7, iw = qrow - 7 * ih;
      v = btab[((ih - jh + 13) * 20 + (iw - jw + 13)) * 6 + h];
    }
    ((float*)ws)[BIAS_F32 + u] = v;
  }
}

// ---------------------------------------------------------------------------
// qkv_kernel: one block (4 waves) per window.
// q, k stored direct to ws (16-lane 32B segments: acceptable coalescing).
// v transposed through LDS: MFMA C-tiles scatter into [32][228] bf16 buffer
// (stride 228 ushorts = 114 dwords, 114%32=18 -> conflict-free scatter),
// one barrier per head, then cooperative FULLY-CONTIGUOUS 14.3KB dump to
// global. Double-buffered so dump(h) overlaps compute(h+1); barrier chain
// guarantees dump(h) done before scatter(h+2) reuses the buffer.
// kv weight B-fragments loaded once per kk, reused across 3 m-tiles.
// ---------------------------------------------------------------------------
__launch_bounds__(256, 3)
__global__ void qkv_kernel(const float* __restrict__ x1,
                           const float* __restrict__ x2,
                           const float* __restrict__ qkv_b,
                           const float* __restrict__ qkv2_b,
                           unsigned short* __restrict__ ws) {
  __shared__ unsigned short vbuf[2][32 * 228];   // 2 x 14,592 B = 29,184 B

  const int tid  = threadIdx.x;
  const int wave = tid >> 6;
  const int lane = tid & 63;
  const int l16  = lane & 15;
  const int quad = lane >> 4;
  const int b    = blockIdx.x;

  const float* x1b = x1 + (size_t)b * (49 * 192);
  const float* x2b = x2 + (size_t)b * (196 * 192);
  unsigned short* qg = ws + QG_U16  + (size_t)b * 6 * 2048;
  unsigned short* kg = ws + KG_U16  + (size_t)b * 6 * 6656;
  unsigned short* vg = ws + VTG_U16 + (size_t)b * 6 * 7168;

  // zero LDS pad keys 208..223 of both buffers once (never scattered over;
  // dump copies keys 0..223 so these must be exact zeros)
  for (int i = tid; i < 512; i += 256) {
    int bu = i >> 8, j = i & 255;        // j: d = j>>3, u32-chunk = j&7
    *(unsigned int*)(&vbuf[bu][(j >> 3) * 228 + 208 + (j & 7) * 2]) = 0u;
  }

  // head-invariant A-fragments, converted ONCE
  bf16x8 x1f[6];
  {
    const int m = wave * 16 + l16;
    const bool mv = (m < 49);
#pragma unroll
    for (int kk = 0; kk < 6; ++kk)
      x1f[kk] = mv ? cvt8(x1b + m * 192 + kk * 32 + quad * 8)
                   : bf16x8{0, 0, 0, 0, 0, 0, 0, 0};
  }
  bf16x8 x2f[3][6];
#pragma unroll
  for (int ti = 0; ti < 3; ++ti) {
    const int m = (wave + ti * 4) * 16 + l16;   // < 192: all rows real
#pragma unroll
    for (int kk = 0; kk < 6; ++kk)
      x2f[ti][kk] = cvt8(x2b + m * 192 + kk * 32 + quad * 8);
  }

  __syncthreads();   // LDS pad zeros visible before first scatter/dump cycle

  for (int h = 0; h < 6; ++h) {
    unsigned short* vb = vbuf[h & 1];
    // ---- q_h = (x1 @ Wq_h + b) * SCALE  -> qg[h][64][32] (pad rows finite)
    {
      f32x4 a0{0.f, 0.f, 0.f, 0.f}, a1{0.f, 0.f, 0.f, 0.f};
#pragma unroll
      for (int kk = 0; kk < 6; ++kk) {
        const unsigned short* wq = ws + WS_QKVT + (h * 32 + l16) * 192 + kk * 32 + quad * 8;
        a0 = MFMA16(x1f[kk], *(const bf16x8*)(wq), a0);
        a1 = MFMA16(x1f[kk], *(const bf16x8*)(wq + 16 * 192), a1);
      }
      const float b0 = qkv_b[h * 32 + l16];
      const float b1 = qkv_b[h * 32 + 16 + l16];
      unsigned short* qh = qg + h * 2048;
#pragma unroll
      for (int r = 0; r < 4; ++r) {
        const int row = wave * 16 + quad * 4 + r;
        qh[row * 32 + l16]      = f2bf((a0[r] + b0) * SCALE_Q);
        qh[row * 32 + 16 + l16] = f2bf((a1[r] + b1) * SCALE_Q);
      }
    }
    const float bk0 = qkv2_b[h * 32 + l16];
    const float bk1 = qkv2_b[h * 32 + 16 + l16];
    const float bv0 = qkv2_b[192 + h * 32 + l16];
    const float bv1 = qkv2_b[192 + h * 32 + 16 + l16];
    unsigned short* kh = kg + h * 6656;
    // ---- k pass: kk-outer, B-fragments loaded once, used by all 3 tiles ----
    {
      f32x4 ka[3][2];
#pragma unroll
      for (int ti = 0; ti < 3; ++ti) {
        ka[ti][0] = f32x4{0.f, 0.f, 0.f, 0.f};
        ka[ti][1] = f32x4{0.f, 0.f, 0.f, 0.f};
      }
#pragma unroll
      for (int kk = 0; kk < 6; ++kk) {
        const unsigned short* wk = ws + WS_QKV2T + (h * 32 + l16) * 192 + kk * 32 + quad * 8;
        bf16x8 w0 = *(const bf16x8*)(wk);
        bf16x8 w1 = *(const bf16x8*)(wk + 16 * 192);
#pragma unroll
        for (int ti = 0; ti < 3; ++ti) {
          ka[ti][0] = MFMA16(x2f[ti][kk], w0, ka[ti][0]);
          ka[ti][1] = MFMA16(x2f[ti][kk], w1, ka[ti][1]);
        }
      }
#pragma unroll
      for (int ti = 0; ti < 3; ++ti) {
#pragma unroll
        for (int r = 0; r < 4; ++r) {
          const int row = (wave + ti * 4) * 16 + quad * 4 + r;   // < 192
          kh[row * 32 + l16]      = f2bf(ka[ti][0][r] + bk0);
          kh[row * 32 + 16 + l16] = f2bf(ka[ti][1][r] + bk1);
        }
      }
    }
    // ---- v pass: same structure; C-tiles scatter into LDS (transpose) ----
    {
      f32x4 va[3][2];
#pragma unroll
      for (int ti = 0; ti < 3; ++ti) {
        va[ti][0] = f32x4{0.f, 0.f, 0.f, 0.f};
        va[ti][1] = f32x4{0.f, 0.f, 0.f, 0.f};
      }
#pragma unroll
      for (int kk = 0; kk < 6; ++kk) {
        const unsigned short* wk = ws + WS_QKV2T + (h * 32 + l16) * 192 + kk * 32 + quad * 8;
        bf16x8 w2 = *(const bf16x8*)(wk + 192 * 192);
        bf16x8 w3 = *(const bf16x8*)(wk + 208 * 192);
#pragma unroll
        for (int ti = 0; ti < 3; ++ti) {
          va[ti][0] = MFMA16(x2f[ti][kk], w2, va[ti][0]);
          va[ti][1] = MFMA16(x2f[ti][kk], w3, va[ti][1]);
        }
      }
#pragma unroll
      for (int ti = 0; ti < 3; ++ti) {
#pragma unroll
        for (int r = 0; r < 4; ++r) {
          const int row = (wave + ti * 4) * 16 + quad * 4 + r;   // key < 192
          vb[l16 * 228 + row]        = f2bf(va[ti][0][r] + bv0);
          vb[(16 + l16) * 228 + row] = f2bf(va[ti][1][r] + bv1);
        }
      }
    }
    // ---- ragged tile (wave 0): rows 192..207; zeros for keys >= 196 ----
    if (wave == 0) {
      f32x4 a0{0.f, 0.f, 0.f, 0.f}, a1{0.f, 0.f, 0.f, 0.f};
      f32x4 a2{0.f, 0.f, 0.f, 0.f}, a3{0.f, 0.f, 0.f, 0.f};
      const int m = 192 + l16;
      const bool mv = (m < 196);
#pragma unroll
      for (int kk = 0; kk < 6; ++kk) {
        bf16x8 a = mv ? cvt8(x2b + m * 192 + kk * 32 + quad * 8)
                      : bf16x8{0, 0, 0, 0, 0, 0, 0, 0};
        const unsigned short* wk = ws + WS_QKV2T + (h * 32 + l16) * 192 + kk * 32 + quad * 8;
        a0 = MFMA16(a, *(const bf16x8*)(wk), a0);
        a1 = MFMA16(a, *(const bf16x8*)(wk + 16 * 192), a1);
        a2 = MFMA16(a, *(const bf16x8*)(wk + 192 * 192), a2);
        a3 = MFMA16(a, *(const bf16x8*)(wk + 208 * 192), a3);
      }
#pragma unroll
      for (int r = 0; r < 4; ++r) {
        const int row = 192 + quad * 4 + r;
        const bool rv = (row < 196);     // rows 196..207 get EXACT zeros
        kh[row * 32 + l16]        = rv ? f2bf(a0[r] + bk0) : (unsigned short)0;
        kh[row * 32 + 16 + l16]   = rv ? f2bf(a1[r] + bk1) : (unsigned short)0;
        vb[l16 * 228 + row]        = rv ? f2bf(a2[r] + bv0) : (unsigned short)0;
        vb[(16 + l16) * 228 + row] = rv ? f2bf(a3[r] + bv1) : (unsigned short)0;
      }
    }
    __syncthreads();   // scatter complete; also orders dump(h-1) vs reuse
    // ---- cooperative dump: LDS [32][228] -> global [32][224], contiguous ----
    {
      unsigned short* vh = vg + h * 7168;
      const unsigned short* sb = vb;
      for (int i = tid; i < 1792; i += 256) {        // 8B chunks, 7 iters
        const int d = i / 56, c = (i - d * 56) * 4;  // c: ushort offset, %4==0
        *(unsigned long long*)(vh + d * 224 + c) =
            *(const unsigned long long*)(sb + d * 228 + c);
      }
    }
  }
}

// ---------------------------------------------------------------------------
// attn2: one independent wave per (window, head). 4 waves/block, NO barriers.
// Per-wave LDS strip [16][232] bf16 for the P C-layout -> A-layout round trip
// (stride 232: 2-way banks = free). k/v/q/bias read straight from ws.
// ---------------------------------------------------------------------------
__launch_bounds__(256, 4)
__global__ void attn2_kernel(const unsigned short* __restrict__ ws,
                             float* __restrict__ out) {
  __shared__ unsigned short ps4[4][16 * 232];   // 29,696 B
  const int tid  = threadIdx.x;
  const int wave = tid >> 6;
  const int lane = tid & 63;
  const int l16  = lane & 15;
  const int quad = lane >> 4;
  const int wid  = blockIdx.x * 4 + wave;       // < 6144
  const int win  = wid / 6, head = wid - win * 6;

  const unsigned short* qb = ws + QG_U16  + (size_t)wid * 2048;
  const unsigned short* kb = ws + KG_U16  + (size_t)wid * 6656;
  const unsigned short* vb = ws + VTG_U16 + (size_t)wid * 7168;
  const float* bbt = (const float*)ws + BIAS_F32 + head * 14336;
  unsigned short* ps = ps4[wave];
  float* ob = out + (size_t)win * 9408 + head * 32;

  // zero strip pad cols 208..231 once (P cols 0..207 rewritten every m-tile)
  for (int i = lane; i < 192; i += 64) {
    int rr = i / 12, cc = (i - rr * 12) * 2;
    *(unsigned int*)(ps + rr * 232 + 208 + cc) = 0u;
  }

  for (int mt = 0; mt < 4; ++mt) {
    // ---- logits = q k^T + bias (bias/mask preloaded as MFMA C-init) ----
    bf16x8 aq = *(const bf16x8*)(qb + (mt * 16 + l16) * 32 + quad * 8);
    f32x4 lg[13];
#pragma unroll
    for (int nt = 0; nt < 13; ++nt)
      lg[nt] = *(const f32x4*)(bbt + (nt * 16 + l16) * 64 + mt * 16 + quad * 4);
#pragma unroll
    for (int nt = 0; nt < 13; ++nt)
      lg[nt] = MFMA16(aq, *(const bf16x8*)(kb + (nt * 16 + l16) * 32 + quad * 8), lg[nt]);

    // ---- row softmax (row = quad*4+r on the 16 lanes of one quad) ----
#pragma unroll
    for (int r = 0; r < 4; ++r) {
      float mx = lg[0][r];
#pragma unroll
      for (int nt = 1; nt < 13; ++nt) mx = fmaxf(mx, lg[nt][r]);
      mx = fmaxf(mx, __shfl_xor(mx, 1));
      mx = fmaxf(mx, __shfl_xor(mx, 2));
      mx = fmaxf(mx, __shfl_xor(mx, 4));
      mx = fmaxf(mx, __shfl_xor(mx, 8));
      float s = 0.f;
#pragma unroll
      for (int nt = 0; nt < 13; ++nt) {
        float p = __expf(lg[nt][r] - mx);
        lg[nt][r] = p;
        s += p;
      }
      s += __shfl_xor(s, 1);
      s += __shfl_xor(s, 2);
      s += __shfl_xor(s, 4);
      s += __shfl_xor(s, 8);
      const float inv = 1.f / s;
      const int row = quad * 4 + r;     // garbage window-rows written too;
#pragma unroll                          // their PV output is discarded below
      for (int nt = 0; nt < 13; ++nt)
        ps[row * 232 + nt * 16 + l16] = f2bf(lg[nt][r] * inv);
    }

    // ---- out tile = P @ V (K padded to 224 with exact zeros) ----
    f32x4 o0{0.f, 0.f, 0.f, 0.f}, o1{0.f, 0.f, 0.f, 0.f};
#pragma unroll
    for (int kk = 0; kk < 7; ++kk) {
      bf16x8 a  = *(const bf16x8*)(ps + l16 * 232 + kk * 32 + quad * 8);
      bf16x8 b0 = *(const bf16x8*)(vb + l16 * 224 + kk * 32 + quad * 8);
      bf16x8 b1 = *(const bf16x8*)(vb + (16 + l16) * 224 + kk * 32 + quad * 8);
      o0 = MFMA16(a, b0, o0);
      o1 = MFMA16(a, b1, o1);
    }
#pragma unroll
    for (int r = 0; r < 4; ++r) {
      const int row = mt * 16 + quad * 4 + r;
      if (row < 49) {
        float* op = ob + row * 192;
        op[l16]      = o0[r];
        op[16 + l16] = o1[r];
      }
    }
  }
}

// ---------------------------------------------------------------------------
// R1 fused attention kernel — retained verbatim as the small-ws fallback.
// ---------------------------------------------------------------------------
__launch_bounds__(256, 2)
__global__ void attn_kernel(const float* __restrict__ x1,
                            const float* __restrict__ x2,
                            const float* __restrict__ qkv_b,
                            const float* __restrict__ qkv2_b,
                            const float* __restrict__ btab,   // [400][6]
                            const unsigned short* __restrict__ ws,
                            float* __restrict__ out) {
  extern __shared__ char smem[];
  unsigned short* ksm = (unsigned short*)(smem);
  unsigned short* vtm = (unsigned short*)(smem + 15680);
  unsigned short* atm = (unsigned short*)(smem + 30528);
  unsigned short* qhm = (unsigned short*)(smem + 60224);

  const int tid  = threadIdx.x;
  const int wave = tid >> 6;
  const int lane = tid & 63;
  const int l16  = lane & 15;
  const int quad = lane >> 4;
  const int b    = blockIdx.x;

  const float* x1b = x1 + (size_t)b * (49 * 192);
  const float* x2b = x2 + (size_t)b * (196 * 192);

  {
    int* z = (int*)(smem + 30528);
    for (int i = tid; i < 29696 / 4; i += 256) z[i] = 0;
    int* z2 = (int*)(smem + 15680);
    for (int i = tid; i < 14848 / 4; i += 256) z2[i] = 0;
  }

  int Pr6[4];
#pragma unroll
  for (int r = 0; r < 4; ++r) {
    int i = wave * 16 + quad * 4 + r;
    if (i > 48) i = 48;
    int ih = i / 7, iw = i - 7 * ih;
    Pr6[r] = (ih * 20 + iw + 273) * 6;
  }
  int qj6[13];
#pragma unroll
  for (int nt = 0; nt < 13; ++nt) {
    int jc = nt * 16 + l16;
    if (jc > 195) jc = 195;
    int jh = jc / 14, jw = jc - 14 * jh;
    qj6[nt] = (jh * 20 + jw) * 6;
  }

  bf16x8 x1f[6];
  {
    const int m = wave * 16 + l16;
    const bool mv = (m < 49);
#pragma unroll
    for (int kk = 0; kk < 6; ++kk) {
      if (mv) x1f[kk] = cvt8(x1b + m * 192 + kk * 32 + quad * 8);
      else    x1f[kk] = bf16x8{0, 0, 0, 0, 0, 0, 0, 0};
    }
  }
  bf16x8 x2f[3][6];
#pragma unroll
  for (int ti = 0; ti < 3; ++ti) {
    const int m = (wave + ti * 4) * 16 + l16;
#pragma unroll
    for (int kk = 0; kk < 6; ++kk)
      x2f[ti][kk] = cvt8(x2b + m * 192 + kk * 32 + quad * 8);
  }

  __syncthreads();

  for (int h = 0; h < 6; ++h) {
    {
      f32x4 acc0{0.f, 0.f, 0.f, 0.f}, acc1{0.f, 0.f, 0.f, 0.f};
#pragma unroll
      for (int kk = 0; kk < 6; ++kk) {
        const unsigned short* wq = ws + WS_QKVT + (h * 32 + l16) * 192 + kk * 32 + quad * 8;
        acc0 = MFMA16(x1f[kk], *(const bf16x8*)(wq), acc0);
        acc1 = MFMA16(x1f[kk], *(const bf16x8*)(wq + 16 * 192), acc1);
      }
      const float bia0 = qkv_b[h * 32 + l16];
      const float bia1 = qkv_b[h * 32 + 16 + l16];
#pragma unroll
      for (int r = 0; r < 4; ++r) {
        const int row = wave * 16 + quad * 4 + r;
        qhm[row * 40 + l16]      = f2bf((acc0[r] + bia0) * SCALE_Q);
        qhm[row * 40 + 16 + l16] = f2bf((acc1[r] + bia1) * SCALE_Q);
      }
    }
    const float bk0 = qkv2_b[h * 32 + l16];
    const float bk1 = qkv2_b[h * 32 + 16 + l16];
    const float bv0 = qkv2_b[192 + h * 32 + l16];
    const float bv1 = qkv2_b[192 + h * 32 + 16 + l16];
#pragma unroll
    for (int ti = 0; ti < 3; ++ti) {
      const int mt = wave + ti * 4;
      f32x4 acc0{0.f, 0.f, 0.f, 0.f}, acc1{0.f, 0.f, 0.f, 0.f};
      f32x4 acc2{0.f, 0.f, 0.f, 0.f}, acc3{0.f, 0.f, 0.f, 0.f};
#pragma unroll
      for (int kk = 0; kk < 6; ++kk) {
        const unsigned short* wk = ws + WS_QKV2T + (h * 32 + l16) * 192 + kk * 32 + quad * 8;
        acc0 = MFMA16(x2f[ti][kk], *(const bf16x8*)(wk), acc0);
        acc1 = MFMA16(x2f[ti][kk], *(const bf16x8*)(wk + 16 * 192), acc1);
        acc2 = MFMA16(x2f[ti][kk], *(const bf16x8*)(wk + 192 * 192), acc2);
        acc3 = MFMA16(x2f[ti][kk], *(const bf16x8*)(wk + 208 * 192), acc3);
      }
#pragma unroll
      for (int r = 0; r < 4; ++r) {
        const int row = mt * 16 + quad * 4 + r;
        ksm[row * 40 + l16]      = f2bf(acc0[r] + bk0);
        ksm[row * 40 + 16 + l16] = f2bf(acc1[r] + bk1);
        vtm[l16 * 232 + row]        = f2bf(acc2[r] + bv0);
        vtm[(16 + l16) * 232 + row] = f2bf(acc3[r] + bv1);
      }
    }
    if (wave == 0) {
      f32x4 acc0{0.f, 0.f, 0.f, 0.f}, acc1{0.f, 0.f, 0.f, 0.f};
      f32x4 acc2{0.f, 0.f, 0.f, 0.f}, acc3{0.f, 0.f, 0.f, 0.f};
      const int m = 192 + l16;
      const bool mv = (m < 196);
#pragma unroll
      for (int kk = 0; kk < 6; ++kk) {
        const int k0 = kk * 32 + quad * 8;
        bf16x8 a;
        if (mv) a = cvt8(x2b + m * 192 + k0);
        else    a = bf16x8{0, 0, 0, 0, 0, 0, 0, 0};
        const unsigned short* wk = ws + WS_QKV2T + (h * 32 + l16) * 192 + k0;
        acc0 = MFMA16(a, *(const bf16x8*)(wk), acc0);
        acc1 = MFMA16(a, *(const bf16x8*)(wk + 16 * 192), acc1);
        acc2 = MFMA16(a, *(const bf16x8*)(wk + 192 * 192), acc2);
        acc3 = MFMA16(a, *(const bf16x8*)(wk + 208 * 192), acc3);
      }
#pragma unroll
      for (int r = 0; r < 4; ++r) {
        const int row = 192 + quad * 4 + r;
        if (row < 196) {
          ksm[row * 40 + l16]      = f2bf(acc0[r] + bk0);
          ksm[row * 40 + 16 + l16] = f2bf(acc1[r] + bk1);
        }
        vtm[l16 * 232 + row]        = f2bf(acc2[r] + bv0);
        vtm[(16 + l16) * 232 + row] = f2bf(acc3[r] + bv1);
      }
    }
    __syncthreads();

    f32x4 lg[13];
    {
      const int m = wave * 16 + l16;
      bf16x8 a = *(const bf16x8*)(qhm + m * 40 + quad * 8);
#pragma unroll
      for (int nt = 0; nt < 12; ++nt) {
#pragma unroll
        for (int r = 0; r < 4; ++r) lg[nt][r] = btab[Pr6[r] - qj6[nt] + h];
      }
#pragma unroll
      for (int r = 0; r < 4; ++r)
        lg[12][r] = (l16 < 4) ? btab[Pr6[r] - qj6[12] + h] : -1e30f;
#pragma unroll
      for (int nt = 0; nt < 13; ++nt) {
        bf16x8 bb = *(const bf16x8*)(ksm + (nt * 16 + l16) * 40 + quad * 8);
        lg[nt] = MFMA16(a, bb, lg[nt]);
      }
#pragma unroll
      for (int r = 0; r < 4; ++r) {
        float mx = lg[0][r];
#pragma unroll
        for (int nt = 1; nt < 13; ++nt) mx = fmaxf(mx, lg[nt][r]);
        mx = fmaxf(mx, __shfl_xor(mx, 1));
        mx = fmaxf(mx, __shfl_xor(mx, 2));
        mx = fmaxf(mx, __shfl_xor(mx, 4));
        mx = fmaxf(mx, __shfl_xor(mx, 8));
        float s = 0.f;
#pragma unroll
        for (int nt = 0; nt < 13; ++nt) {
          float p = __expf(lg[nt][r] - mx);
          lg[nt][r] = p;
          s += p;
        }
        s += __shfl_xor(s, 1);
        s += __shfl_xor(s, 2);
        s += __shfl_xor(s, 4);
        s += __shfl_xor(s, 8);
        const float inv = 1.f / s;
        const int row = wave * 16 + quad * 4 + r;
        if (row < 49) {
#pragma unroll
          for (int nt = 0; nt < 13; ++nt)
            atm[row * 232 + nt * 16 + l16] = f2bf(lg[nt][r] * inv);
        }
      }
    }
    {
      f32x4 o0{0.f, 0.f, 0.f, 0.f}, o1{0.f, 0.f, 0.f, 0.f};
      const int m = wave * 16 + l16;
#pragma unroll
      for (int kk = 0; kk < 7; ++kk) {
        const int k0 = kk * 32 + quad * 8;
        bf16x8 a  = *(const bf16x8*)(atm + m * 232 + k0);
        bf16x8 b0 = *(const bf16x8*)(vtm + l16 * 232 + k0);
        bf16x8 b1 = *(const bf16x8*)(vtm + (16 + l16) * 232 + k0);
        o0 = MFMA16(a, b0, o0);
        o1 = MFMA16(a, b1, o1);
      }
#pragma unroll
      for (int r = 0; r < 4; ++r) {
        const int row = wave * 16 + quad * 4 + r;
        if (row < 49) {
          float* op = out + (size_t)b * 9408 + row * 192 + h * 32;
          op[l16]      = o0[r];
          op[16 + l16] = o1[r];
        }
      }
    }
    __syncthreads();
  }
}

// ---------------------------------------------------------------------------
// proj: in-place on d_out, NO LDS, NO barrier. Each wave's read-row set
// (m = wave*16+l16) equals its write-row set (wave*16+quad*4+r), and program
// order keeps all reads before stores -> in-place is race-free.
// Split-bf16 3-pass MFMA: C += Ah*Bh + Ah*Bl + Al*Bh (~fp32 quality).
// ---------------------------------------------------------------------------
__launch_bounds__(256, 4)
__global__ void proj_kernel(const float* __restrict__ proj_b,
                            const unsigned short* __restrict__ ws,
                            float* __restrict__ out) {
  const int tid  = threadIdx.x;
  const int wave = tid >> 6;
  const int lane = tid & 63;
  const int l16  = lane & 15;
  const int quad = lane >> 4;
  const size_t base = (size_t)blockIdx.x * 64 * 192;

  f32x4 pacc[12];
#pragma unroll
  for (int nt = 0; nt < 12; ++nt) pacc[nt] = f32x4{0.f, 0.f, 0.f, 0.f};

  const int m = wave * 16 + l16;
  const float* ap0 = out + base + m * 192;
#pragma unroll
  for (int kk = 0; kk < 6; ++kk) {
    const int k0 = kk * 32 + quad * 8;
    float4 v0 = *(const float4*)(ap0 + k0);
    float4 v1 = *(const float4*)(ap0 + k0 + 4);
    float f[8] = {v0.x, v0.y, v0.z, v0.w, v1.x, v1.y, v1.z, v1.w};
    union { bf16x8 v; unsigned short s[8]; } H, L;
#pragma unroll
    for (int j = 0; j < 8; ++j) {
      H.s[j] = f2bf(f[j]);
      L.s[j] = f2bf(f[j] - bf2f(H.s[j]));
    }
#pragma unroll
    for (int nt = 0; nt < 12; ++nt) {
      bf16x8 bh = *(const bf16x8*)(ws + WS_PROJH + (nt * 16 + l16) * 192 + k0);
      bf16x8 bl = *(const bf16x8*)(ws + WS_PROJL + (nt * 16 + l16) * 192 + k0);
      pacc[nt] = MFMA16(H.v, bh, pacc[nt]);
      pacc[nt] = MFMA16(H.v, bl, pacc[nt]);
      pacc[nt] = MFMA16(L.v, bh, pacc[nt]);
    }
  }
#pragma unroll
  for (int nt = 0; nt < 12; ++nt) {
    const float pb = proj_b[nt * 16 + l16];
#pragma unroll
    for (int r = 0; r < 4; ++r) {
      const int row = wave * 16 + quad * 4 + r;
      out[base + row * 192 + nt * 16 + l16] = pacc[nt][r] + pb;
    }
  }
}

// ---------------------------------------------------------------------------
extern "C" void kernel_launch(void* const* d_in, const int* in_sizes, int n_in,
                              void* d_out, int out_size, void* d_ws, size_t ws_size,
                              hipStream_t stream) {
  const float* x1     = (const float*)d_in[0];
  const float* x2     = (const float*)d_in[1];
  const float* qkv_w  = (const float*)d_in[2];
  const float* qkv_b  = (const float*)d_in[3];
  const float* qkv2_w = (const float*)d_in[4];
  const float* qkv2_b = (const float*)d_in[5];
  const float* proj_w = (const float*)d_in[6];
  const float* proj_b = (const float*)d_in[7];
  const float* btab   = (const float*)d_in[8];
  unsigned short* ws  = (unsigned short*)d_ws;
  float* out          = (float*)d_out;
  (void)in_sizes; (void)n_in; (void)out_size;

  if (ws_size >= WS_NEEDED) {
    prep_kernel<<<dim3(912), dim3(256), 0, stream>>>(qkv_w, qkv2_w, proj_w, btab, ws);
    qkv_kernel<<<dim3(1024), dim3(256), 0, stream>>>(x1, x2, qkv_b, qkv2_b, ws);
    attn2_kernel<<<dim3(1536), dim3(256), 0, stream>>>(ws, out);
    proj_kernel<<<dim3(784), dim3(256), 0, stream>>>(proj_b, ws, out);
  } else {
    prep_kernel<<<dim3(576), dim3(256), 0, stream>>>(qkv_w, qkv2_w, proj_w, btab, ws);
    attn_kernel<<<dim3(1024), dim3(256), 65344, stream>>>(x1, x2, qkv_b, qkv2_b,
                                                          btab, ws, out);
    proj_kernel<<<dim3(784), dim3(256), 0, stream>>>(proj_b, ws, out);
  }
}

// Round 4
// 574.674 us; speedup vs baseline: 1.4157x; 1.3242x over previous
//
#include <hip/hip_runtime.h>

// ---------------------------------------------------------------------------
// WindowAttention on MI355X (gfx950).
// R4 restructure: every kernel so far was latency-bound (all pipes <10%,
// occupancy ~24%). New pipeline:
//   prep       : weight transpose + bf16 cast + bias table [6][224][64] f32
//                (ws needs only ~0.7 MB now).
//   fused_attn : ONE BLOCK PER (window, head) = 6144 blocks, 4 waves, 36.6KB
//                LDS -> 4 blocks/CU. qkv GEMM -> LDS -> QK^T -> softmax -> PV
//                with only TWO barriers. P strips reuse the dead k/q LDS
//                region (two-pass PV). XCD swizzle co-locates the 6 head-
//                blocks of a window on one XCD so the 6x x2 re-read is L2-hot.
//                Kills the 195MB write + 195MB read q/k/v round trip of R2/R3.
//   proj       : in-place, 1568 blocks x 32 rows, nt split across wave pairs
//                (one barrier orders reads before in-place writes),
//                split-bf16 3-pass MFMA for ~fp32 quality.
// All matmuls v_mfma_f32_16x16x32_bf16. Fragment layouts (m89/m91-verified):
// A/B: elem j -> [lane&15][quad*8+j] (K-major); C/D: col=lane&15, row=quad*4+r.
// ---------------------------------------------------------------------------

typedef __attribute__((ext_vector_type(8))) short bf16x8;
typedef __attribute__((ext_vector_type(4))) float f32x4;

#define MFMA16(a, b, c) __builtin_amdgcn_mfma_f32_16x16x32_bf16((a), (b), (c), 0, 0, 0)

// ws layout. ushort-unit offsets for bf16 regions, f32-unit for bias table.
#define WS_QKVT  0         // [192][192]  qkv_w^T   bf16
#define WS_QKV2T 36864     // [384][192]  qkv2_w^T  bf16
#define WS_PROJH 110592    // [192][192]  proj_w^T  hi bf16
#define WS_PROJL 147456    // [192][192]  proj_w^T  lo bf16
#define BIAS_F32 92160     // byte 368,640: [6][224][64] f32 bias table

#define SCALE_Q 0.17677669529663687f   // 32^-0.5

__device__ __forceinline__ unsigned short f2bf(float f) {
  unsigned int u = __float_as_uint(f);
  u += 0x7fffu + ((u >> 16) & 1u);     // round-to-nearest-even
  return (unsigned short)(u >> 16);
}
__device__ __forceinline__ float bf2f(unsigned short s) {
  return __uint_as_float(((unsigned int)s) << 16);
}
// load 8 consecutive fp32 (32B, aligned) -> bf16x8 fragment
__device__ __forceinline__ bf16x8 cvt8(const float* __restrict__ p) {
  union { bf16x8 v; unsigned short s[8]; } U;
  float4 v0 = *(const float4*)p;
  float4 v1 = *(const float4*)(p + 4);
  U.s[0] = f2bf(v0.x); U.s[1] = f2bf(v0.y); U.s[2] = f2bf(v0.z); U.s[3] = f2bf(v0.w);
  U.s[4] = f2bf(v1.x); U.s[5] = f2bf(v1.y); U.s[6] = f2bf(v1.z); U.s[7] = f2bf(v1.w);
  return U.v;
}

// ---------------------------------------------------------------------------
// prep: W^T bf16 casts + bias table.
// biasT[h][key][qrow] f32: -1e30 for key>=196 (mask), 0 for qrow>=49 (pad),
// else btab[rel_idx(qrow,key)*6+h]. Matches attn C-layout: float4 over qrow.
// ---------------------------------------------------------------------------
__global__ void prep_kernel(const float* __restrict__ qkv_w,
                            const float* __restrict__ qkv2_w,
                            const float* __restrict__ proj_w,
                            const float* __restrict__ btab,
                            unsigned short* __restrict__ ws) {
  int t = blockIdx.x * 256 + threadIdx.x;
  if (t < 36864) {                       // qkv_w (192x192), reads coalesced
    int k = t / 192, n = t % 192;
    ws[WS_QKVT + n * 192 + k] = f2bf(qkv_w[t]);
  } else if (t < 110592) {               // qkv2_w (192x384)
    int u = t - 36864;
    int k = u / 384, n = u % 384;
    ws[WS_QKV2T + n * 192 + k] = f2bf(qkv2_w[u]);
  } else if (t < 147456) {               // proj_w (192x192) hi/lo split
    int u = t - 110592;
    int k = u / 192, n = u % 192;
    float p = proj_w[u];
    unsigned short hi = f2bf(p);
    ws[WS_PROJH + n * 192 + k] = hi;
    ws[WS_PROJL + n * 192 + k] = f2bf(p - bf2f(hi));
  } else if (t < 233472) {               // bias table [6][224][64] f32
    int u = t - 147456;
    int h = u / 14336;
    int r2 = u - h * 14336;
    int key = r2 >> 6, qrow = r2 & 63;
    float v;
    if (key >= 196)      v = -1e30f;     // key-pad mask
    else if (qrow >= 49) v = 0.f;        // query pad: finite, rows discarded
    else {
      int jh = key / 14, jw = key - 14 * jh;
      int ih = qrow / 7, iw = qrow - 7 * ih;
      v = btab[((ih - jh + 13) * 20 + (iw - jw + 13)) * 6 + h];
    }
    ((float*)ws)[BIAS_F32 + u] = v;
  }
}

// ---------------------------------------------------------------------------
// fused_attn: one block per (window, head). 256 threads = 4 waves.
// LDS (static, 36,608 B -> 4 blocks/CU):
//   ksm [208][40] bf16 @ 0       (16,640 B)  k, K-major in d (rows 196+ = 0)
//   qhm [64][40]  bf16 @ 16,640  ( 5,120 B)  q
//   vtm [32][232] bf16 @ 21,760  (14,848 B)  v^T [d][key] (keys 196..223 = 0)
//   P strips: after barrier #2 the ksm+qhm region (dead) is reused as 4
//   per-wave strips at wave*4352 (pass A [16][136], pass B [16][104]).
// Barriers: #1 after phase 1 (k/v/q + pads visible), #2 after QK^T reads
// (before P overwrites region A). That's ALL.
// XCD swizzle: logical = (bid%8)*768 + bid/8 -> each XCD owns 128 contiguous
// windows; the 6 head-blocks of a window are dispatched adjacently on the
// same XCD => x2 window (150KB) is L2-hot for 5 of its 6 readers.
// ---------------------------------------------------------------------------
__launch_bounds__(256, 4)
__global__ void fused_attn_kernel(const float* __restrict__ x1,
                                  const float* __restrict__ x2,
                                  const float* __restrict__ qkv_b,
                                  const float* __restrict__ qkv2_b,
                                  const unsigned short* __restrict__ ws,
                                  float* __restrict__ out) {
  __shared__ __align__(16) char smem[36608];
  unsigned short* ksm = (unsigned short*)(smem);
  unsigned short* qhm = (unsigned short*)(smem + 16640);
  unsigned short* vtm = (unsigned short*)(smem + 21760);

  const int tid  = threadIdx.x;
  const int wave = tid >> 6;
  const int lane = tid & 63;
  const int l16  = lane & 15;
  const int quad = lane >> 4;

  const int logical = (blockIdx.x & 7) * 768 + (blockIdx.x >> 3);  // 6144=8*768
  const int win  = logical / 6;
  const int h    = logical - win * 6;

  const float* x1b = x1 + (size_t)win * (49 * 192);
  const float* x2b = x2 + (size_t)win * (196 * 192);
  const float* bbt = (const float*)ws + BIAS_F32 + h * 14336;

  // zero vtm pad keys 208..223 (32 rows x 8 u32 = 256 u32, one per thread)
  {
    int d = tid >> 3, c = tid & 7;
    *(unsigned int*)(vtm + d * 232 + 208 + c * 2) = 0u;
  }

  // ---------------- Phase 1a: q_h = (x1 @ Wq_h + b) * SCALE -> qhm ----------
  {
    f32x4 qa0{0.f, 0.f, 0.f, 0.f}, qa1{0.f, 0.f, 0.f, 0.f};
    const int mq = wave * 16 + l16;
    const bool mv = (mq < 49);
#pragma unroll
    for (int kk = 0; kk < 6; ++kk) {
      bf16x8 a = mv ? cvt8(x1b + mq * 192 + kk * 32 + quad * 8)
                    : bf16x8{0, 0, 0, 0, 0, 0, 0, 0};
      const unsigned short* wq = ws + WS_QKVT + (h * 32 + l16) * 192 + kk * 32 + quad * 8;
      qa0 = MFMA16(a, *(const bf16x8*)(wq), qa0);
      qa1 = MFMA16(a, *(const bf16x8*)(wq + 16 * 192), qa1);
    }
    const float b0 = qkv_b[h * 32 + l16];
    const float b1 = qkv_b[h * 32 + 16 + l16];
#pragma unroll
    for (int r = 0; r < 4; ++r) {
      const int row = wave * 16 + quad * 4 + r;     // <= 63 in-bounds
      qhm[row * 40 + l16]      = f2bf((qa0[r] + b0) * SCALE_Q);
      qhm[row * 40 + 16 + l16] = f2bf((qa1[r] + b1) * SCALE_Q);
    }
  }
  // ---------------- Phase 1b: k_h, v_h for tiles {w, w+4, w+8} -> LDS -------
  const float bk0 = qkv2_b[h * 32 + l16];
  const float bk1 = qkv2_b[h * 32 + 16 + l16];
  const float bv0 = qkv2_b[192 + h * 32 + l16];
  const float bv1 = qkv2_b[192 + h * 32 + 16 + l16];
  {
    f32x4 ka0[3], ka1[3], va0[3], va1[3];
#pragma unroll
    for (int ti = 0; ti < 3; ++ti) {
      ka0[ti] = f32x4{0.f, 0.f, 0.f, 0.f}; ka1[ti] = f32x4{0.f, 0.f, 0.f, 0.f};
      va0[ti] = f32x4{0.f, 0.f, 0.f, 0.f}; va1[ti] = f32x4{0.f, 0.f, 0.f, 0.f};
    }
#pragma unroll 2
    for (int kk = 0; kk < 6; ++kk) {
      const unsigned short* wk = ws + WS_QKV2T + (h * 32 + l16) * 192 + kk * 32 + quad * 8;
      bf16x8 w0 = *(const bf16x8*)(wk);
      bf16x8 w1 = *(const bf16x8*)(wk + 16 * 192);
      bf16x8 w2 = *(const bf16x8*)(wk + 192 * 192);
      bf16x8 w3 = *(const bf16x8*)(wk + 208 * 192);
#pragma unroll
      for (int ti = 0; ti < 3; ++ti) {
        bf16x8 a = cvt8(x2b + ((ti * 4 + wave) * 16 + l16) * 192 + kk * 32 + quad * 8);
        ka0[ti] = MFMA16(a, w0, ka0[ti]);
        ka1[ti] = MFMA16(a, w1, ka1[ti]);
        va0[ti] = MFMA16(a, w2, va0[ti]);
        va1[ti] = MFMA16(a, w3, va1[ti]);
      }
    }
#pragma unroll
    for (int ti = 0; ti < 3; ++ti) {
#pragma unroll
      for (int r = 0; r < 4; ++r) {
        const int row = (ti * 4 + wave) * 16 + quad * 4 + r;   // < 192
        ksm[row * 40 + l16]        = f2bf(ka0[ti][r] + bk0);
        ksm[row * 40 + 16 + l16]   = f2bf(ka1[ti][r] + bk1);
        vtm[l16 * 232 + row]        = f2bf(va0[ti][r] + bv0);
        vtm[(16 + l16) * 232 + row] = f2bf(va1[ti][r] + bv1);
      }
    }
  }
  // ragged tile (wave 0): rows 192..207; exact zeros for rows >= 196
  if (wave == 0) {
    f32x4 a0{0.f, 0.f, 0.f, 0.f}, a1{0.f, 0.f, 0.f, 0.f};
    f32x4 a2{0.f, 0.f, 0.f, 0.f}, a3{0.f, 0.f, 0.f, 0.f};
    const int m = 192 + l16;
    const bool mv = (m < 196);
#pragma unroll 2
    for (int kk = 0; kk < 6; ++kk) {
      bf16x8 a = mv ? cvt8(x2b + m * 192 + kk * 32 + quad * 8)
                    : bf16x8{0, 0, 0, 0, 0, 0, 0, 0};
      const unsigned short* wk = ws + WS_QKV2T + (h * 32 + l16) * 192 + kk * 32 + quad * 8;
      a0 = MFMA16(a, *(const bf16x8*)(wk), a0);
      a1 = MFMA16(a, *(const bf16x8*)(wk + 16 * 192), a1);
      a2 = MFMA16(a, *(const bf16x8*)(wk + 192 * 192), a2);
      a3 = MFMA16(a, *(const bf16x8*)(wk + 208 * 192), a3);
    }
#pragma unroll
    for (int r = 0; r < 4; ++r) {
      const int row = 192 + quad * 4 + r;
      const bool rv = (row < 196);
      ksm[row * 40 + l16]        = rv ? f2bf(a0[r] + bk0) : (unsigned short)0;
      ksm[row * 40 + 16 + l16]   = rv ? f2bf(a1[r] + bk1) : (unsigned short)0;
      vtm[l16 * 232 + row]        = rv ? f2bf(a2[r] + bv0) : (unsigned short)0;
      vtm[(16 + l16) * 232 + row] = rv ? f2bf(a3[r] + bv1) : (unsigned short)0;
    }
  }
  __syncthreads();   // barrier #1: k/v/q + all pads visible

  // ---------------- Phase 2: logits = q k^T + bias, softmax -----------------
  f32x4 lg[13];
  {
    bf16x8 aq = *(const bf16x8*)(qhm + (wave * 16 + l16) * 40 + quad * 8);
#pragma unroll
    for (int nt = 0; nt < 13; ++nt)
      lg[nt] = *(const f32x4*)(bbt + (nt * 16 + l16) * 64 + wave * 16 + quad * 4);
#pragma unroll
    for (int nt = 0; nt < 13; ++nt)
      lg[nt] = MFMA16(aq, *(const bf16x8*)(ksm + (nt * 16 + l16) * 40 + quad * 8), lg[nt]);
    // row softmax: row (query) = quad*4+r, spread over the 16 lanes of a quad
#pragma unroll
    for (int r = 0; r < 4; ++r) {
      float mx = lg[0][r];
#pragma unroll
      for (int nt = 1; nt < 13; ++nt) mx = fmaxf(mx, lg[nt][r]);
      mx = fmaxf(mx, __shfl_xor(mx, 1));
      mx = fmaxf(mx, __shfl_xor(mx, 2));
      mx = fmaxf(mx, __shfl_xor(mx, 4));
      mx = fmaxf(mx, __shfl_xor(mx, 8));
      float s = 0.f;
#pragma unroll
      for (int nt = 0; nt < 13; ++nt) {
        float p = __expf(lg[nt][r] - mx);
        lg[nt][r] = p;
        s += p;
      }
      s += __shfl_xor(s, 1);
      s += __shfl_xor(s, 2);
      s += __shfl_xor(s, 4);
      s += __shfl_xor(s, 8);
      const float inv = 1.f / s;
#pragma unroll
      for (int nt = 0; nt < 13; ++nt) lg[nt][r] *= inv;
    }
  }
  __syncthreads();   // barrier #2: all ksm/qhm reads done; region A reusable

  // ---------------- Phase 3: out = P @ V, two passes through P strip --------
  unsigned short* ps = (unsigned short*)(smem + wave * 4352);   // private strip
  f32x4 o0{0.f, 0.f, 0.f, 0.f}, o1{0.f, 0.f, 0.f, 0.f};
  // pass A: keys 0..127, strip [16][136]
#pragma unroll
  for (int r = 0; r < 4; ++r) {
    const int row = quad * 4 + r;
#pragma unroll
    for (int nt = 0; nt < 8; ++nt)
      ps[row * 136 + nt * 16 + l16] = f2bf(lg[nt][r]);
  }
#pragma unroll
  for (int kk = 0; kk < 4; ++kk) {
    bf16x8 a  = *(const bf16x8*)(ps + l16 * 136 + kk * 32 + quad * 8);
    bf16x8 b0 = *(const bf16x8*)(vtm + l16 * 232 + kk * 32 + quad * 8);
    bf16x8 b1 = *(const bf16x8*)(vtm + (16 + l16) * 232 + kk * 32 + quad * 8);
    o0 = MFMA16(a, b0, o0);
    o1 = MFMA16(a, b1, o1);
  }
  // pass B: keys 128..223 (cols 80..95 are the exact-zero 208..223 pad),
  // strip [16][104]
#pragma unroll
  for (int r = 0; r < 4; ++r) {
    const int row = quad * 4 + r;
#pragma unroll
    for (int nt = 8; nt < 13; ++nt)
      ps[row * 104 + (nt - 8) * 16 + l16] = f2bf(lg[nt][r]);
    ps[row * 104 + 80 + l16] = 0;
  }
#pragma unroll
  for (int kk = 0; kk < 3; ++kk) {
    bf16x8 a  = *(const bf16x8*)(ps + l16 * 104 + kk * 32 + quad * 8);
    bf16x8 b0 = *(const bf16x8*)(vtm + l16 * 232 + (4 + kk) * 32 + quad * 8);
    bf16x8 b1 = *(const bf16x8*)(vtm + (16 + l16) * 232 + (4 + kk) * 32 + quad * 8);
    o0 = MFMA16(a, b0, o0);
    o1 = MFMA16(a, b1, o1);
  }
  // write pre-projection output fp32 (proj is in-place on d_out)
  {
    float* ob = out + (size_t)win * 9408 + h * 32;
#pragma unroll
    for (int r = 0; r < 4; ++r) {
      const int row = wave * 16 + quad * 4 + r;
      if (row < 49) {
        float* op = ob + row * 192;
        op[l16]      = o0[r];
        op[16 + l16] = o1[r];
      }
    }
  }
}

// ---------------------------------------------------------------------------
// proj: in-place on d_out. 1568 blocks x 32 rows (50176 = 1568*32 exactly).
// Waves: (wave&1) selects 16-row group, (wave>>1) selects nt-half (cols 0-95
// vs 96-191). One barrier orders ALL in-place reads before ANY writes (a
// wave's write-cols overlap another wave's read-cols of the same rows).
// Split-bf16 3-pass MFMA: C += Ah*Bh + Ah*Bl + Al*Bh (~fp32 quality).
// ---------------------------------------------------------------------------
__launch_bounds__(256, 4)
__global__ void proj_kernel(const float* __restrict__ proj_b,
                            const unsigned short* __restrict__ ws,
                            float* __restrict__ out) {
  const int tid  = threadIdx.x;
  const int wave = tid >> 6;
  const int lane = tid & 63;
  const int l16  = lane & 15;
  const int quad = lane >> 4;
  const int rowg = (wave & 1) * 16;
  const int nth  = (wave >> 1) * 6;
  const size_t base = (size_t)blockIdx.x * 32 * 192;

  f32x4 pacc[6];
#pragma unroll
  for (int nt = 0; nt < 6; ++nt) pacc[nt] = f32x4{0.f, 0.f, 0.f, 0.f};

  const float* ap0 = out + base + (rowg + l16) * 192;
#pragma unroll 2
  for (int kk = 0; kk < 6; ++kk) {
    const int k0 = kk * 32 + quad * 8;
    float4 v0 = *(const float4*)(ap0 + k0);
    float4 v1 = *(const float4*)(ap0 + k0 + 4);
    float f[8] = {v0.x, v0.y, v0.z, v0.w, v1.x, v1.y, v1.z, v1.w};
    union { bf16x8 v; unsigned short s[8]; } H, L;
#pragma unroll
    for (int j = 0; j < 8; ++j) {
      H.s[j] = f2bf(f[j]);
      L.s[j] = f2bf(f[j] - bf2f(H.s[j]));
    }
#pragma unroll
    for (int nt = 0; nt < 6; ++nt) {
      bf16x8 bh = *(const bf16x8*)(ws + WS_PROJH + ((nth + nt) * 16 + l16) * 192 + k0);
      bf16x8 bl = *(const bf16x8*)(ws + WS_PROJL + ((nth + nt) * 16 + l16) * 192 + k0);
      pacc[nt] = MFMA16(H.v, bh, pacc[nt]);
      pacc[nt] = MFMA16(H.v, bl, pacc[nt]);
      pacc[nt] = MFMA16(L.v, bh, pacc[nt]);
    }
  }
  __syncthreads();   // all in-place reads complete before any writes
#pragma unroll
  for (int nt = 0; nt < 6; ++nt) {
    const float pb = proj_b[(nth + nt) * 16 + l16];
#pragma unroll
    for (int r = 0; r < 4; ++r) {
      const int row = rowg + quad * 4 + r;
      out[base + row * 192 + (nth + nt) * 16 + l16] = pacc[nt][r] + pb;
    }
  }
}

// ---------------------------------------------------------------------------
extern "C" void kernel_launch(void* const* d_in, const int* in_sizes, int n_in,
                              void* d_out, int out_size, void* d_ws, size_t ws_size,
                              hipStream_t stream) {
  const float* x1     = (const float*)d_in[0];
  const float* x2     = (const float*)d_in[1];
  const float* qkv_w  = (const float*)d_in[2];
  const float* qkv_b  = (const float*)d_in[3];
  const float* qkv2_w = (const float*)d_in[4];
  const float* qkv2_b = (const float*)d_in[5];
  const float* proj_w = (const float*)d_in[6];
  const float* proj_b = (const float*)d_in[7];
  const float* btab   = (const float*)d_in[8];
  unsigned short* ws  = (unsigned short*)d_ws;
  float* out          = (float*)d_out;
  (void)in_sizes; (void)n_in; (void)out_size; (void)ws_size;

  prep_kernel<<<dim3(912), dim3(256), 0, stream>>>(qkv_w, qkv2_w, proj_w, btab, ws);
  fused_attn_kernel<<<dim3(6144), dim3(256), 0, stream>>>(x1, x2, qkv_b, qkv2_b,
                                                          ws, out);
  proj_kernel<<<dim3(1568), dim3(256), 0, stream>>>(proj_b, ws, out);
}

// Round 6
// 566.997 us; speedup vs baseline: 1.4349x; 1.0135x over previous
//
#include <hip/hip_runtime.h>

// ---------------------------------------------------------------------------
// WindowAttention on MI355X (gfx950).
// R6 == R5 resubmitted (R5 bench died on container acquire, never measured).
// Changes vs R4 (last measured, 575us total; fused: MfmaUtil 5.8/VALU 20.5/
// HBM 5.5 => issue+latency bound; ~200us of total is proj below top-5 cutoff):
//   1. cast_kernel pre-casts x1/x2 to bf16 ONCE (memory-bound ~50us). The
//      fused kernel loads bf16x8 directly: removes ~770 conversion-VALU per
//      wave from the critical path (was recomputed 6x, once per head-block)
//      and halves its fetch bytes.
//   2. fused epilogue writes pre-projection output SPLIT into bf16 hi/lo to
//      ws (bit-identical to proj's old read-time split). proj becomes a pure
//      bf16 GEMM: no f2bf, no in-place hazard, no barrier, no LDS.
// Pipeline: prep (weights+bias) ; cast ; fused_attn (1 block per
// (window,head), 2 barriers, 36.6KB LDS, XCD swizzle) ; proj (bf16 3-pass).
// Fallback (ws < 136MB): R4 path (proven): fused_f32 + in-place proj.
// All matmuls v_mfma_f32_16x16x32_bf16. Fragment layouts (m89/m91-verified):
// A/B: elem j -> [lane&15][quad*8+j] (K-major); C/D: col=lane&15, row=quad*4+r.
// ---------------------------------------------------------------------------

typedef __attribute__((ext_vector_type(8))) short bf16x8;
typedef __attribute__((ext_vector_type(4))) float f32x4;

#define MFMA16(a, b, c) __builtin_amdgcn_mfma_f32_16x16x32_bf16((a), (b), (c), 0, 0, 0)

// ws layout. u16-unit offsets unless noted.
#define WS_QKVT  0          // [192][192] qkv_w^T  bf16
#define WS_QKV2T 36864      // [384][192] qkv2_w^T bf16
#define WS_PROJH 110592     // [192][192] proj_w^T hi bf16
#define WS_PROJL 147456     // [192][192] proj_w^T lo bf16
#define BIAS_F32 92160      // f32-unit offset (byte 368,640): [6][224][64] f32
#define X1C_U16  524288     // x1 bf16 [1024*49][192]   (9,633,792 u16)
#define X2C_U16  10158080   // x2 bf16 [1024*196][192]  (38,535,168 u16)
#define OH_U16   48693248   // attn out hi bf16 [50176][192]
#define OL_U16   58327040   // attn out lo bf16 [50176][192]
#define WS_NEEDED 135921664ull   // bytes

#define SCALE_Q 0.17677669529663687f   // 32^-0.5

__device__ __forceinline__ unsigned short f2bf(float f) {
  unsigned int u = __float_as_uint(f);
  u += 0x7fffu + ((u >> 16) & 1u);     // round-to-nearest-even
  return (unsigned short)(u >> 16);
}
__device__ __forceinline__ float bf2f(unsigned short s) {
  return __uint_as_float(((unsigned int)s) << 16);
}
__device__ __forceinline__ bf16x8 cvt8(const float* __restrict__ p) {
  union { bf16x8 v; unsigned short s[8]; } U;
  float4 v0 = *(const float4*)p;
  float4 v1 = *(const float4*)(p + 4);
  U.s[0] = f2bf(v0.x); U.s[1] = f2bf(v0.y); U.s[2] = f2bf(v0.z); U.s[3] = f2bf(v0.w);
  U.s[4] = f2bf(v1.x); U.s[5] = f2bf(v1.y); U.s[6] = f2bf(v1.z); U.s[7] = f2bf(v1.w);
  return U.v;
}

// ---------------------------------------------------------------------------
// prep: W^T bf16 casts + bias table [6][224][64] f32 (C-layout friendly).
// ---------------------------------------------------------------------------
__global__ void prep_kernel(const float* __restrict__ qkv_w,
                            const float* __restrict__ qkv2_w,
                            const float* __restrict__ proj_w,
                            const float* __restrict__ btab,
                            unsigned short* __restrict__ ws) {
  int t = blockIdx.x * 256 + threadIdx.x;
  if (t < 36864) {
    int k = t / 192, n = t % 192;
    ws[WS_QKVT + n * 192 + k] = f2bf(qkv_w[t]);
  } else if (t < 110592) {
    int u = t - 36864;
    int k = u / 384, n = u % 384;
    ws[WS_QKV2T + n * 192 + k] = f2bf(qkv2_w[u]);
  } else if (t < 147456) {
    int u = t - 110592;
    int k = u / 192, n = u % 192;
    float p = proj_w[u];
    unsigned short hi = f2bf(p);
    ws[WS_PROJH + n * 192 + k] = hi;
    ws[WS_PROJL + n * 192 + k] = f2bf(p - bf2f(hi));
  } else if (t < 233472) {
    int u = t - 147456;
    int h = u / 14336;
    int r2 = u - h * 14336;
    int key = r2 >> 6, qrow = r2 & 63;
    float v;
    if (key >= 196)      v = -1e30f;     // key-pad mask
    else if (qrow >= 49) v = 0.f;        // query pad (rows discarded later)
    else {
      int jh = key / 14, jw = key - 14 * jh;
      int ih = qrow / 7, iw = qrow - 7 * ih;
      v = btab[((ih - jh + 13) * 20 + (iw - jw + 13)) * 6 + h];
    }
    ((float*)ws)[BIAS_F32 + u] = v;
  }
}

// ---------------------------------------------------------------------------
// cast: x1,x2 fp32 -> bf16 in ws. Pure streaming, 16B loads, 16B stores.
// ---------------------------------------------------------------------------
__launch_bounds__(256, 8)
__global__ void cast_kernel(const float* __restrict__ x1,
                            const float* __restrict__ x2,
                            unsigned short* __restrict__ ws) {
  const int T = 6021120;                 // (9,633,792 + 38,535,168)/8
  for (int i = blockIdx.x * 256 + threadIdx.x; i < T; i += gridDim.x * 256) {
    if (i < 1204224) {
      *(bf16x8*)(ws + X1C_U16 + (size_t)i * 8) = cvt8(x1 + (size_t)i * 8);
    } else {
      size_t j = (size_t)(i - 1204224);
      *(bf16x8*)(ws + X2C_U16 + j * 8) = cvt8(x2 + j * 8);
    }
  }
}

// ---------------------------------------------------------------------------
// fused_attn (fast path): one block per (window, head). 4 waves, 36,608B LDS
// (4 blocks/CU). x1/x2 read as bf16 directly (no conversion VALU). Epilogue
// writes bf16 hi/lo pre-projection output to ws.
// LDS: ksm [208][40] @0 (16,640B) | qhm [64][40] @16,640 (5,120B) |
//      vtm [32][232] @21,760 (14,848B). P strips reuse ksm/qhm after bar #2.
// XCD swizzle: 6 head-blocks of a window adjacent on one XCD (x2 L2-hot).
// ---------------------------------------------------------------------------
__launch_bounds__(256, 4)
__global__ void fused_attn_kernel(const float* __restrict__ qkv_b,
                                  const float* __restrict__ qkv2_b,
                                  unsigned short* __restrict__ ws) {
  __shared__ __align__(16) char smem[36608];
  unsigned short* ksm = (unsigned short*)(smem);
  unsigned short* qhm = (unsigned short*)(smem + 16640);
  unsigned short* vtm = (unsigned short*)(smem + 21760);

  const int tid  = threadIdx.x;
  const int wave = tid >> 6;
  const int lane = tid & 63;
  const int l16  = lane & 15;
  const int quad = lane >> 4;

  const int logical = (blockIdx.x & 7) * 768 + (blockIdx.x >> 3);  // 6144=8*768
  const int win  = logical / 6;
  const int h    = logical - win * 6;

  const unsigned short* x1c = ws + X1C_U16 + (size_t)win * (49 * 192);
  const unsigned short* x2c = ws + X2C_U16 + (size_t)win * (196 * 192);
  const float* bbt = (const float*)ws + BIAS_F32 + h * 14336;

  // zero vtm pad keys 208..223 (32 rows x 8 u32 = 256 u32, one per thread)
  {
    int d = tid >> 3, c = tid & 7;
    *(unsigned int*)(vtm + d * 232 + 208 + c * 2) = 0u;
  }

  // ---------------- Phase 1a: q_h = (x1 @ Wq_h + b) * SCALE -> qhm ----------
  {
    f32x4 qa0{0.f, 0.f, 0.f, 0.f}, qa1{0.f, 0.f, 0.f, 0.f};
    const int mq = wave * 16 + l16;
    const bool mv = (mq < 49);
#pragma unroll
    for (int kk = 0; kk < 6; ++kk) {
      bf16x8 a = mv ? *(const bf16x8*)(x1c + mq * 192 + kk * 32 + quad * 8)
                    : bf16x8{0, 0, 0, 0, 0, 0, 0, 0};
      const unsigned short* wq = ws + WS_QKVT + (h * 32 + l16) * 192 + kk * 32 + quad * 8;
      qa0 = MFMA16(a, *(const bf16x8*)(wq), qa0);
      qa1 = MFMA16(a, *(const bf16x8*)(wq + 16 * 192), qa1);
    }
    const float b0 = qkv_b[h * 32 + l16];
    const float b1 = qkv_b[h * 32 + 16 + l16];
#pragma unroll
    for (int r = 0; r < 4; ++r) {
      const int row = wave * 16 + quad * 4 + r;
      qhm[row * 40 + l16]      = f2bf((qa0[r] + b0) * SCALE_Q);
      qhm[row * 40 + 16 + l16] = f2bf((qa1[r] + b1) * SCALE_Q);
    }
  }
  // ---------------- Phase 1b: k_h, v_h for tiles {w, w+4, w+8} -> LDS -------
  const float bk0 = qkv2_b[h * 32 + l16];
  const float bk1 = qkv2_b[h * 32 + 16 + l16];
  const float bv0 = qkv2_b[192 + h * 32 + l16];
  const float bv1 = qkv2_b[192 + h * 32 + 16 + l16];
  {
    f32x4 ka0[3], ka1[3], va0[3], va1[3];
#pragma unroll
    for (int ti = 0; ti < 3; ++ti) {
      ka0[ti] = f32x4{0.f, 0.f, 0.f, 0.f}; ka1[ti] = f32x4{0.f, 0.f, 0.f, 0.f};
      va0[ti] = f32x4{0.f, 0.f, 0.f, 0.f}; va1[ti] = f32x4{0.f, 0.f, 0.f, 0.f};
    }
#pragma unroll 2
    for (int kk = 0; kk < 6; ++kk) {
      const unsigned short* wk = ws + WS_QKV2T + (h * 32 + l16) * 192 + kk * 32 + quad * 8;
      bf16x8 w0 = *(const bf16x8*)(wk);
      bf16x8 w1 = *(const bf16x8*)(wk + 16 * 192);
      bf16x8 w2 = *(const bf16x8*)(wk + 192 * 192);
      bf16x8 w3 = *(const bf16x8*)(wk + 208 * 192);
#pragma unroll
      for (int ti = 0; ti < 3; ++ti) {
        bf16x8 a = *(const bf16x8*)(x2c + ((ti * 4 + wave) * 16 + l16) * 192 + kk * 32 + quad * 8);
        ka0[ti] = MFMA16(a, w0, ka0[ti]);
        ka1[ti] = MFMA16(a, w1, ka1[ti]);
        va0[ti] = MFMA16(a, w2, va0[ti]);
        va1[ti] = MFMA16(a, w3, va1[ti]);
      }
    }
#pragma unroll
    for (int ti = 0; ti < 3; ++ti) {
#pragma unroll
      for (int r = 0; r < 4; ++r) {
        const int row = (ti * 4 + wave) * 16 + quad * 4 + r;   // < 192
        ksm[row * 40 + l16]        = f2bf(ka0[ti][r] + bk0);
        ksm[row * 40 + 16 + l16]   = f2bf(ka1[ti][r] + bk1);
        vtm[l16 * 232 + row]        = f2bf(va0[ti][r] + bv0);
        vtm[(16 + l16) * 232 + row] = f2bf(va1[ti][r] + bv1);
      }
    }
  }
  // ragged tile (wave 0): rows 192..207; exact zeros for rows >= 196
  if (wave == 0) {
    f32x4 a0{0.f, 0.f, 0.f, 0.f}, a1{0.f, 0.f, 0.f, 0.f};
    f32x4 a2{0.f, 0.f, 0.f, 0.f}, a3{0.f, 0.f, 0.f, 0.f};
    const int m = 192 + l16;
    const bool mv = (m < 196);
#pragma unroll 2
    for (int kk = 0; kk < 6; ++kk) {
      bf16x8 a = mv ? *(const bf16x8*)(x2c + m * 192 + kk * 32 + quad * 8)
                    : bf16x8{0, 0, 0, 0, 0, 0, 0, 0};
      const unsigned short* wk = ws + WS_QKV2T + (h * 32 + l16) * 192 + kk * 32 + quad * 8;
      a0 = MFMA16(a, *(const bf16x8*)(wk), a0);
      a1 = MFMA16(a, *(const bf16x8*)(wk + 16 * 192), a1);
      a2 = MFMA16(a, *(const bf16x8*)(wk + 192 * 192), a2);
      a3 = MFMA16(a, *(const bf16x8*)(wk + 208 * 192), a3);
    }
#pragma unroll
    for (int r = 0; r < 4; ++r) {
      const int row = 192 + quad * 4 + r;
      const bool rv = (row < 196);
      ksm[row * 40 + l16]        = rv ? f2bf(a0[r] + bk0) : (unsigned short)0;
      ksm[row * 40 + 16 + l16]   = rv ? f2bf(a1[r] + bk1) : (unsigned short)0;
      vtm[l16 * 232 + row]        = rv ? f2bf(a2[r] + bv0) : (unsigned short)0;
      vtm[(16 + l16) * 232 + row] = rv ? f2bf(a3[r] + bv1) : (unsigned short)0;
    }
  }
  __syncthreads();   // barrier #1: k/v/q + all pads visible

  // ---------------- Phase 2: logits = q k^T + bias, softmax -----------------
  f32x4 lg[13];
  {
    bf16x8 aq = *(const bf16x8*)(qhm + (wave * 16 + l16) * 40 + quad * 8);
#pragma unroll
    for (int nt = 0; nt < 13; ++nt)
      lg[nt] = *(const f32x4*)(bbt + (nt * 16 + l16) * 64 + wave * 16 + quad * 4);
#pragma unroll
    for (int nt = 0; nt < 13; ++nt)
      lg[nt] = MFMA16(aq, *(const bf16x8*)(ksm + (nt * 16 + l16) * 40 + quad * 8), lg[nt]);
#pragma unroll
    for (int r = 0; r < 4; ++r) {
      float mx = lg[0][r];
#pragma unroll
      for (int nt = 1; nt < 13; ++nt) mx = fmaxf(mx, lg[nt][r]);
      mx = fmaxf(mx, __shfl_xor(mx, 1));
      mx = fmaxf(mx, __shfl_xor(mx, 2));
      mx = fmaxf(mx, __shfl_xor(mx, 4));
      mx = fmaxf(mx, __shfl_xor(mx, 8));
      float s = 0.f;
#pragma unroll
      for (int nt = 0; nt < 13; ++nt) {
        float p = __expf(lg[nt][r] - mx);
        lg[nt][r] = p;
        s += p;
      }
      s += __shfl_xor(s, 1);
      s += __shfl_xor(s, 2);
      s += __shfl_xor(s, 4);
      s += __shfl_xor(s, 8);
      const float inv = 1.f / s;
#pragma unroll
      for (int nt = 0; nt < 13; ++nt) lg[nt][r] *= inv;
    }
  }
  __syncthreads();   // barrier #2: ksm/qhm reads done; region reusable

  // ---------------- Phase 3: out = P @ V, two passes through P strip --------
  unsigned short* ps = (unsigned short*)(smem + wave * 4352);
  f32x4 o0{0.f, 0.f, 0.f, 0.f}, o1{0.f, 0.f, 0.f, 0.f};
#pragma unroll
  for (int r = 0; r < 4; ++r) {
    const int row = quad * 4 + r;
#pragma unroll
    for (int nt = 0; nt < 8; ++nt)
      ps[row * 136 + nt * 16 + l16] = f2bf(lg[nt][r]);
  }
#pragma unroll
  for (int kk = 0; kk < 4; ++kk) {
    bf16x8 a  = *(const bf16x8*)(ps + l16 * 136 + kk * 32 + quad * 8);
    bf16x8 b0 = *(const bf16x8*)(vtm + l16 * 232 + kk * 32 + quad * 8);
    bf16x8 b1 = *(const bf16x8*)(vtm + (16 + l16) * 232 + kk * 32 + quad * 8);
    o0 = MFMA16(a, b0, o0);
    o1 = MFMA16(a, b1, o1);
  }
#pragma unroll
  for (int r = 0; r < 4; ++r) {
    const int row = quad * 4 + r;
#pragma unroll
    for (int nt = 8; nt < 13; ++nt)
      ps[row * 104 + (nt - 8) * 16 + l16] = f2bf(lg[nt][r]);
    ps[row * 104 + 80 + l16] = 0;
  }
#pragma unroll
  for (int kk = 0; kk < 3; ++kk) {
    bf16x8 a  = *(const bf16x8*)(ps + l16 * 104 + kk * 32 + quad * 8);
    bf16x8 b0 = *(const bf16x8*)(vtm + l16 * 232 + (4 + kk) * 32 + quad * 8);
    bf16x8 b1 = *(const bf16x8*)(vtm + (16 + l16) * 232 + (4 + kk) * 32 + quad * 8);
    o0 = MFMA16(a, b0, o0);
    o1 = MFMA16(a, b1, o1);
  }
  // epilogue: hi/lo bf16 split (bit-identical to proj's old read-time split)
  {
    unsigned short* oh = ws + OH_U16 + (size_t)win * 49 * 192 + h * 32;
    unsigned short* ol = ws + OL_U16 + (size_t)win * 49 * 192 + h * 32;
#pragma unroll
    for (int r = 0; r < 4; ++r) {
      const int row = wave * 16 + quad * 4 + r;
      if (row < 49) {
        float v0 = o0[r], v1 = o1[r];
        unsigned short h0 = f2bf(v0), h1 = f2bf(v1);
        oh[row * 192 + l16]      = h0;
        ol[row * 192 + l16]      = f2bf(v0 - bf2f(h0));
        oh[row * 192 + 16 + l16] = h1;
        ol[row * 192 + 16 + l16] = f2bf(v1 - bf2f(h1));
      }
    }
  }
}

// ---------------------------------------------------------------------------
// proj (fast path): pure bf16 GEMM. Reads hi/lo A from ws, writes d_out.
// No f2bf, no barrier, no LDS, no in-place hazard. 1568 blocks x 32 rows;
// (wave&1) = row group, (wave>>1) = col half. 3-pass: Ah*Bh + Ah*Bl + Al*Bh.
// ---------------------------------------------------------------------------
__launch_bounds__(256, 4)
__global__ void proj_kernel(const float* __restrict__ proj_b,
                            const unsigned short* __restrict__ ws,
                            float* __restrict__ out) {
  const int tid  = threadIdx.x;
  const int wave = tid >> 6;
  const int lane = tid & 63;
  const int l16  = lane & 15;
  const int quad = lane >> 4;
  const int rowg = (wave & 1) * 16;
  const int nth  = (wave >> 1) * 6;
  const size_t rbase = (size_t)blockIdx.x * 32;

  const unsigned short* ah = ws + OH_U16 + (rbase + rowg + l16) * 192;
  const unsigned short* al = ws + OL_U16 + (rbase + rowg + l16) * 192;

  f32x4 pacc[6];
#pragma unroll
  for (int nt = 0; nt < 6; ++nt) pacc[nt] = f32x4{0.f, 0.f, 0.f, 0.f};

#pragma unroll 2
  for (int kk = 0; kk < 6; ++kk) {
    const int k0 = kk * 32 + quad * 8;
    bf16x8 AH = *(const bf16x8*)(ah + k0);
    bf16x8 AL = *(const bf16x8*)(al + k0);
#pragma unroll
    for (int nt = 0; nt < 6; ++nt) {
      bf16x8 bh = *(const bf16x8*)(ws + WS_PROJH + ((nth + nt) * 16 + l16) * 192 + k0);
      bf16x8 bl = *(const bf16x8*)(ws + WS_PROJL + ((nth + nt) * 16 + l16) * 192 + k0);
      pacc[nt] = MFMA16(AH, bh, pacc[nt]);
      pacc[nt] = MFMA16(AH, bl, pacc[nt]);
      pacc[nt] = MFMA16(AL, bh, pacc[nt]);
    }
  }
#pragma unroll
  for (int nt = 0; nt < 6; ++nt) {
    const float pb = proj_b[(nth + nt) * 16 + l16];
#pragma unroll
    for (int r = 0; r < 4; ++r) {
      const int row = rowg + quad * 4 + r;
      out[(rbase + row) * 192 + (nth + nt) * 16 + l16] = pacc[nt][r] + pb;
    }
  }
}

// ---------------------------------------------------------------------------
// Fallback path (ws too small): R4 kernels, retained verbatim.
// ---------------------------------------------------------------------------
__launch_bounds__(256, 4)
__global__ void fused_attn_f32_kernel(const float* __restrict__ x1,
                                      const float* __restrict__ x2,
                                      const float* __restrict__ qkv_b,
                                      const float* __restrict__ qkv2_b,
                                      const unsigned short* __restrict__ ws,
                                      float* __restrict__ out) {
  __shared__ __align__(16) char smem[36608];
  unsigned short* ksm = (unsigned short*)(smem);
  unsigned short* qhm = (unsigned short*)(smem + 16640);
  unsigned short* vtm = (unsigned short*)(smem + 21760);

  const int tid  = threadIdx.x;
  const int wave = tid >> 6;
  const int lane = tid & 63;
  const int l16  = lane & 15;
  const int quad = lane >> 4;

  const int logical = (blockIdx.x & 7) * 768 + (blockIdx.x >> 3);
  const int win  = logical / 6;
  const int h    = logical - win * 6;

  const float* x1b = x1 + (size_t)win * (49 * 192);
  const float* x2b = x2 + (size_t)win * (196 * 192);
  const float* bbt = (const float*)ws + BIAS_F32 + h * 14336;

  {
    int d = tid >> 3, c = tid & 7;
    *(unsigned int*)(vtm + d * 232 + 208 + c * 2) = 0u;
  }
  {
    f32x4 qa0{0.f, 0.f, 0.f, 0.f}, qa1{0.f, 0.f, 0.f, 0.f};
    const int mq = wave * 16 + l16;
    const bool mv = (mq < 49);
#pragma unroll
    for (int kk = 0; kk < 6; ++kk) {
      bf16x8 a = mv ? cvt8(x1b + mq * 192 + kk * 32 + quad * 8)
                    : bf16x8{0, 0, 0, 0, 0, 0, 0, 0};
      const unsigned short* wq = ws + WS_QKVT + (h * 32 + l16) * 192 + kk * 32 + quad * 8;
      qa0 = MFMA16(a, *(const bf16x8*)(wq), qa0);
      qa1 = MFMA16(a, *(const bf16x8*)(wq + 16 * 192), qa1);
    }
    const float b0 = qkv_b[h * 32 + l16];
    const float b1 = qkv_b[h * 32 + 16 + l16];
#pragma unroll
    for (int r = 0; r < 4; ++r) {
      const int row = wave * 16 + quad * 4 + r;
      qhm[row * 40 + l16]      = f2bf((qa0[r] + b0) * SCALE_Q);
      qhm[row * 40 + 16 + l16] = f2bf((qa1[r] + b1) * SCALE_Q);
    }
  }
  const float bk0 = qkv2_b[h * 32 + l16];
  const float bk1 = qkv2_b[h * 32 + 16 + l16];
  const float bv0 = qkv2_b[192 + h * 32 + l16];
  const float bv1 = qkv2_b[192 + h * 32 + 16 + l16];
  {
    f32x4 ka0[3], ka1[3], va0[3], va1[3];
#pragma unroll
    for (int ti = 0; ti < 3; ++ti) {
      ka0[ti] = f32x4{0.f, 0.f, 0.f, 0.f}; ka1[ti] = f32x4{0.f, 0.f, 0.f, 0.f};
      va0[ti] = f32x4{0.f, 0.f, 0.f, 0.f}; va1[ti] = f32x4{0.f, 0.f, 0.f, 0.f};
    }
#pragma unroll 2
    for (int kk = 0; kk < 6; ++kk) {
      const unsigned short* wk = ws + WS_QKV2T + (h * 32 + l16) * 192 + kk * 32 + quad * 8;
      bf16x8 w0 = *(const bf16x8*)(wk);
      bf16x8 w1 = *(const bf16x8*)(wk + 16 * 192);
      bf16x8 w2 = *(const bf16x8*)(wk + 192 * 192);
      bf16x8 w3 = *(const bf16x8*)(wk + 208 * 192);
#pragma unroll
      for (int ti = 0; ti < 3; ++ti) {
        bf16x8 a = cvt8(x2b + ((ti * 4 + wave) * 16 + l16) * 192 + kk * 32 + quad * 8);
        ka0[ti] = MFMA16(a, w0, ka0[ti]);
        ka1[ti] = MFMA16(a, w1, ka1[ti]);
        va0[ti] = MFMA16(a, w2, va0[ti]);
        va1[ti] = MFMA16(a, w3, va1[ti]);
      }
    }
#pragma unroll
    for (int ti = 0; ti < 3; ++ti) {
#pragma unroll
      for (int r = 0; r < 4; ++r) {
        const int row = (ti * 4 + wave) * 16 + quad * 4 + r;
        ksm[row * 40 + l16]        = f2bf(ka0[ti][r] + bk0);
        ksm[row * 40 + 16 + l16]   = f2bf(ka1[ti][r] + bk1);
        vtm[l16 * 232 + row]        = f2bf(va0[ti][r] + bv0);
        vtm[(16 + l16) * 232 + row] = f2bf(va1[ti][r] + bv1);
      }
    }
  }
  if (wave == 0) {
    f32x4 a0{0.f, 0.f, 0.f, 0.f}, a1{0.f, 0.f, 0.f, 0.f};
    f32x4 a2{0.f, 0.f, 0.f, 0.f}, a3{0.f, 0.f, 0.f, 0.f};
    const int m = 192 + l16;
    const bool mv = (m < 196);
#pragma unroll 2
    for (int kk = 0; kk < 6; ++kk) {
      bf16x8 a = mv ? cvt8(x2b + m * 192 + kk * 32 + quad * 8)
                    : bf16x8{0, 0, 0, 0, 0, 0, 0, 0};
      const unsigned short* wk = ws + WS_QKV2T + (h * 32 + l16) * 192 + kk * 32 + quad * 8;
      a0 = MFMA16(a, *(const bf16x8*)(wk), a0);
      a1 = MFMA16(a, *(const bf16x8*)(wk + 16 * 192), a1);
      a2 = MFMA16(a, *(const bf16x8*)(wk + 192 * 192), a2);
      a3 = MFMA16(a, *(const bf16x8*)(wk + 208 * 192), a3);
    }
#pragma unroll
    for (int r = 0; r < 4; ++r) {
      const int row = 192 + quad * 4 + r;
      const bool rv = (row < 196);
      ksm[row * 40 + l16]        = rv ? f2bf(a0[r] + bk0) : (unsigned short)0;
      ksm[row * 40 + 16 + l16]   = rv ? f2bf(a1[r] + bk1) : (unsigned short)0;
      vtm[l16 * 232 + row]        = rv ? f2bf(a2[r] + bv0) : (unsigned short)0;
      vtm[(16 + l16) * 232 + row] = rv ? f2bf(a3[r] + bv1) : (unsigned short)0;
    }
  }
  __syncthreads();

  f32x4 lg[13];
  {
    bf16x8 aq = *(const bf16x8*)(qhm + (wave * 16 + l16) * 40 + quad * 8);
#pragma unroll
    for (int nt = 0; nt < 13; ++nt)
      lg[nt] = *(const f32x4*)(bbt + (nt * 16 + l16) * 64 + wave * 16 + quad * 4);
#pragma unroll
    for (int nt = 0; nt < 13; ++nt)
      lg[nt] = MFMA16(aq, *(const bf16x8*)(ksm + (nt * 16 + l16) * 40 + quad * 8), lg[nt]);
#pragma unroll
    for (int r = 0; r < 4; ++r) {
      float mx = lg[0][r];
#pragma unroll
      for (int nt = 1; nt < 13; ++nt) mx = fmaxf(mx, lg[nt][r]);
      mx = fmaxf(mx, __shfl_xor(mx, 1));
      mx = fmaxf(mx, __shfl_xor(mx, 2));
      mx = fmaxf(mx, __shfl_xor(mx, 4));
      mx = fmaxf(mx, __shfl_xor(mx, 8));
      float s = 0.f;
#pragma unroll
      for (int nt = 0; nt < 13; ++nt) {
        float p = __expf(lg[nt][r] - mx);
        lg[nt][r] = p;
        s += p;
      }
      s += __shfl_xor(s, 1);
      s += __shfl_xor(s, 2);
      s += __shfl_xor(s, 4);
      s += __shfl_xor(s, 8);
      const float inv = 1.f / s;
#pragma unroll
      for (int nt = 0; nt < 13; ++nt) lg[nt][r] *= inv;
    }
  }
  __syncthreads();

  unsigned short* ps = (unsigned short*)(smem + wave * 4352);
  f32x4 o0{0.f, 0.f, 0.f, 0.f}, o1{0.f, 0.f, 0.f, 0.f};
#pragma unroll
  for (int r = 0; r < 4; ++r) {
    const int row = quad * 4 + r;
#pragma unroll
    for (int nt = 0; nt < 8; ++nt)
      ps[row * 136 + nt * 16 + l16] = f2bf(lg[nt][r]);
  }
#pragma unroll
  for (int kk = 0; kk < 4; ++kk) {
    bf16x8 a  = *(const bf16x8*)(ps + l16 * 136 + kk * 32 + quad * 8);
    bf16x8 b0 = *(const bf16x8*)(vtm + l16 * 232 + kk * 32 + quad * 8);
    bf16x8 b1 = *(const bf16x8*)(vtm + (16 + l16) * 232 + kk * 32 + quad * 8);
    o0 = MFMA16(a, b0, o0);
    o1 = MFMA16(a, b1, o1);
  }
#pragma unroll
  for (int r = 0; r < 4; ++r) {
    const int row = quad * 4 + r;
#pragma unroll
    for (int nt = 8; nt < 13; ++nt)
      ps[row * 104 + (nt - 8) * 16 + l16] = f2bf(lg[nt][r]);
    ps[row * 104 + 80 + l16] = 0;
  }
#pragma unroll
  for (int kk = 0; kk < 3; ++kk) {
    bf16x8 a  = *(const bf16x8*)(ps + l16 * 104 + kk * 32 + quad * 8);
    bf16x8 b0 = *(const bf16x8*)(vtm + l16 * 232 + (4 + kk) * 32 + quad * 8);
    bf16x8 b1 = *(const bf16x8*)(vtm + (16 + l16) * 232 + (4 + kk) * 32 + quad * 8);
    o0 = MFMA16(a, b0, o0);
    o1 = MFMA16(a, b1, o1);
  }
  {
    float* ob = out + (size_t)win * 9408 + h * 32;
#pragma unroll
    for (int r = 0; r < 4; ++r) {
      const int row = wave * 16 + quad * 4 + r;
      if (row < 49) {
        float* op = ob + row * 192;
        op[l16]      = o0[r];
        op[16 + l16] = o1[r];
      }
    }
  }
}

__launch_bounds__(256, 4)
__global__ void proj_inplace_kernel(const float* __restrict__ proj_b,
                                    const unsigned short* __restrict__ ws,
                                    float* __restrict__ out) {
  const int tid  = threadIdx.x;
  const int wave = tid >> 6;
  const int lane = tid & 63;
  const int l16  = lane & 15;
  const int quad = lane >> 4;
  const int rowg = (wave & 1) * 16;
  const int nth  = (wave >> 1) * 6;
  const size_t base = (size_t)blockIdx.x * 32 * 192;

  f32x4 pacc[6];
#pragma unroll
  for (int nt = 0; nt < 6; ++nt) pacc[nt] = f32x4{0.f, 0.f, 0.f, 0.f};

  const float* ap0 = out + base + (rowg + l16) * 192;
#pragma unroll 2
  for (int kk = 0; kk < 6; ++kk) {
    const int k0 = kk * 32 + quad * 8;
    float4 v0 = *(const float4*)(ap0 + k0);
    float4 v1 = *(const float4*)(ap0 + k0 + 4);
    float f[8] = {v0.x, v0.y, v0.z, v0.w, v1.x, v1.y, v1.z, v1.w};
    union { bf16x8 v; unsigned short s[8]; } H, L;
#pragma unroll
    for (int j = 0; j < 8; ++j) {
      H.s[j] = f2bf(f[j]);
      L.s[j] = f2bf(f[j] - bf2f(H.s[j]));
    }
#pragma unroll
    for (int nt = 0; nt < 6; ++nt) {
      bf16x8 bh = *(const bf16x8*)(ws + WS_PROJH + ((nth + nt) * 16 + l16) * 192 + k0);
      bf16x8 bl = *(const bf16x8*)(ws + WS_PROJL + ((nth + nt) * 16 + l16) * 192 + k0);
      pacc[nt] = MFMA16(H.v, bh, pacc[nt]);
      pacc[nt] = MFMA16(H.v, bl, pacc[nt]);
      pacc[nt] = MFMA16(L.v, bh, pacc[nt]);
    }
  }
  __syncthreads();
#pragma unroll
  for (int nt = 0; nt < 6; ++nt) {
    const float pb = proj_b[(nth + nt) * 16 + l16];
#pragma unroll
    for (int r = 0; r < 4; ++r) {
      const int row = rowg + quad * 4 + r;
      out[base + row * 192 + (nth + nt) * 16 + l16] = pacc[nt][r] + pb;
    }
  }
}

// ---------------------------------------------------------------------------
extern "C" void kernel_launch(void* const* d_in, const int* in_sizes, int n_in,
                              void* d_out, int out_size, void* d_ws, size_t ws_size,
                              hipStream_t stream) {
  const float* x1     = (const float*)d_in[0];
  const float* x2     = (const float*)d_in[1];
  const float* qkv_w  = (const float*)d_in[2];
  const float* qkv_b  = (const float*)d_in[3];
  const float* qkv2_w = (const float*)d_in[4];
  const float* qkv2_b = (const float*)d_in[5];
  const float* proj_w = (const float*)d_in[6];
  const float* proj_b = (const float*)d_in[7];
  const float* btab   = (const float*)d_in[8];
  unsigned short* ws  = (unsigned short*)d_ws;
  float* out          = (float*)d_out;
  (void)in_sizes; (void)n_in; (void)out_size;

  prep_kernel<<<dim3(912), dim3(256), 0, stream>>>(qkv_w, qkv2_w, proj_w, btab, ws);
  if (ws_size >= WS_NEEDED) {
    cast_kernel<<<dim3(2048), dim3(256), 0, stream>>>(x1, x2, ws);
    fused_attn_kernel<<<dim3(6144), dim3(256), 0, stream>>>(qkv_b, qkv2_b, ws);
    proj_kernel<<<dim3(1568), dim3(256), 0, stream>>>(proj_b, ws, out);
  } else {
    fused_attn_f32_kernel<<<dim3(6144), dim3(256), 0, stream>>>(x1, x2, qkv_b,
                                                                qkv2_b, ws, out);
    proj_inplace_kernel<<<dim3(1568), dim3(256), 0, stream>>>(proj_b, ws, out);
  }
}